// Round 1
// baseline (1882.791 us; speedup 1.0000x reference)
//
#include <hip/hip_runtime.h>

#define NN 100000   // nodes
#define NE 1000000  // edges (divisible by 64)
#define NT 200000   // target edges (divisible by 64)
#define SCB 391     // ceil(NN/256) scan blocks

typedef __attribute__((ext_vector_type(8))) short short8;
typedef __attribute__((ext_vector_type(4))) float f32x4;

__device__ __forceinline__ unsigned short f2b(float x) {  // fp32 -> bf16 RNE
  union { float f; unsigned int u; } v; v.f = x;
  unsigned int r = v.u + 0x7fffu + ((v.u >> 16) & 1u);
  return (unsigned short)(r >> 16);
}
__device__ __forceinline__ float b2f(unsigned short x) {
  union { unsigned int u; float f; } v; v.u = ((unsigned int)x) << 16;
  return v.f;
}
__device__ __forceinline__ float uif(unsigned int u) {
  union { unsigned int u; float f; } v; v.u = u; return v.f;
}

// ---------------------------------------------------------------------------
// Weight prep: up to two fp32 sources [K][C] -> bf16 transposed tile
// [rows][104]; row c<C from A col c, C<=c<2C from B col c-C, rest zero.
// ---------------------------------------------------------------------------
struct PrepTab {
  const float* a[14]; const float* b[14];
  int K[14], C[14], rows[14], off[14];
};

__global__ __launch_bounds__(256) void prep_w(PrepTab tab, unsigned short* wT) {
  int s = blockIdx.x;
  const float* A = tab.a[s];
  const float* B = tab.b[s];
  int K = tab.K[s], C = tab.C[s], rows = tab.rows[s];
  unsigned short* dst = wT + tab.off[s];
  int n = rows * 104;
  for (int i = threadIdx.x; i < n; i += 256) {
    int c = i / 104, k = i - c * 104;
    float v = 0.0f;
    if (k < K) {
      if (c < C) v = A[k * C + c];
      else if (B && c < 2 * C) v = B[k * C + (c - C)];
    }
    dst[i] = f2b(v);
  }
}

// ---------------------------------------------------------------------------
// Generic MFMA row-GEMM: out[R,C] = act(in (+add)) @ W + bias
// AIN: 0=f32, 1=f32+add, 2=relu(f32), 3=bf16 input.
// ROUT bit0=relu, bit1=bf16 out, bit2=also write bf16 mirror to out2.
// ---------------------------------------------------------------------------
template<int K, int KSTEPS, int CT, int C, int AIN, int ROUT>
__global__ __launch_bounds__(256) void mfma_gemm(
    const void* __restrict__ in, const float* __restrict__ add,
    const unsigned short* __restrict__ Bt, const float* __restrict__ bias,
    void* __restrict__ outp, void* __restrict__ out2, int R)
{
  constexpr int CR = CT * 16;
  __shared__ __align__(16) unsigned short As[64 * 104];
  __shared__ __align__(16) unsigned short Bs[CR * 104];
  __shared__ float bs[CR];
  const int t = threadIdx.x;
  const int r0 = blockIdx.x * 64;
  for (int i = t; i < CT * 208; i += 256) ((uint4*)Bs)[i] = ((const uint4*)Bt)[i];
  if (t < CR) bs[t] = (bias && t < C) ? bias[t] : 0.0f;
  constexpr int KH = KSTEPS * 16;  // float2 slots per row
  for (int i = t; i < 64 * KH; i += 256) {
    int r = i / KH, kk = (i - r * KH) * 2;
    int rg = r0 + r;
    unsigned short u0 = 0, u1 = 0;
    if (rg < R && kk < K) {
      if constexpr (AIN == 3) {
        unsigned int u = ((const unsigned int*)in)[((size_t)rg * K + kk) >> 1];
        u0 = u & 0xffffu; u1 = u >> 16;
      } else {
        float2 f = *(const float2*)((const float*)in + (size_t)rg * K + kk);
        float v0 = f.x, v1 = f.y;
        if constexpr (AIN == 1) {
          float2 g = *(const float2*)(add + (size_t)rg * K + kk);
          v0 += g.x; v1 += g.y;
        }
        if constexpr (AIN == 2) { v0 = fmaxf(v0, 0.f); v1 = fmaxf(v1, 0.f); }
        u0 = f2b(v0); u1 = f2b(v1);
      }
    }
    As[r * 104 + kk] = u0; As[r * 104 + kk + 1] = u1;
  }
  __syncthreads();
  const int lane = t & 63, w = t >> 6, m = lane & 15, q = lane >> 4;
  f32x4 acc[CT] = {};
  const unsigned short* Ap = As + (w * 16 + m) * 104 + q * 8;
  const unsigned short* Bp = Bs + m * 104 + q * 8;
#pragma unroll
  for (int ks = 0; ks < KSTEPS; ks++) {
    short8 a = *(const short8*)(Ap + ks * 32);
#pragma unroll
    for (int ct = 0; ct < CT; ct++) {
      short8 b = *(const short8*)(Bp + ct * 16 * 104 + ks * 32);
      acc[ct] = __builtin_amdgcn_mfma_f32_16x16x32_bf16(a, b, acc[ct], 0, 0, 0);
    }
  }
#pragma unroll
  for (int ct = 0; ct < CT; ct++) {
    int c = ct * 16 + m;
    if (c < C) {
      float bv = bs[c];
#pragma unroll
      for (int r2 = 0; r2 < 4; r2++) {
        int row = r0 + w * 16 + q * 4 + r2;
        if (row < R) {
          float v = acc[ct][r2] + bv;
          if constexpr ((ROUT & 1) != 0) v = fmaxf(v, 0.f);
          if constexpr ((ROUT & 2) != 0)
            ((unsigned short*)outp)[(size_t)row * C + c] = f2b(v);
          else
            ((float*)outp)[(size_t)row * C + c] = v;
          if constexpr ((ROUT & 4) != 0)
            ((unsigned short*)out2)[(size_t)row * C + c] = f2b(v);
        }
      }
    }
  }
}

// ---------------------------------------------------------------------------
// CSR build: histogram + 3-pass coalesced scan + fill
// ---------------------------------------------------------------------------
__global__ __launch_bounds__(256) void hist_kernel(const int* __restrict__ ei,
                                                   int* __restrict__ deg)
{
  int e = blockIdx.x * 256 + threadIdx.x;
  if (e < NE) atomicAdd(&deg[ei[NE + e]], 1);
}

__global__ __launch_bounds__(256) void blocksum_k(const int* __restrict__ deg,
                                                  int* __restrict__ bsum)
{
  __shared__ int red[256];
  const int t = threadIdx.x;
  int i = blockIdx.x * 256 + t;
  red[t] = (i < NN) ? deg[i] : 0;
  __syncthreads();
  for (int s = 128; s > 0; s >>= 1) {
    if (t < s) red[t] += red[t + s];
    __syncthreads();
  }
  if (t == 0) bsum[blockIdx.x] = red[0];
}

__global__ __launch_bounds__(512) void scansums_k(int* __restrict__ bsum,
                                                  int* __restrict__ rowptr)
{
  __shared__ int s[512];
  const int t = threadIdx.x;
  s[t] = (t < SCB) ? bsum[t] : 0;
  __syncthreads();
  for (int off = 1; off < 512; off <<= 1) {
    int v = (t >= off) ? s[t - off] : 0;
    __syncthreads();
    s[t] += v;
    __syncthreads();
  }
  if (t < SCB) bsum[t] = (t == 0) ? 0 : s[t - 1];  // exclusive
  if (t == 0) rowptr[NN] = NE;
}

__global__ __launch_bounds__(256) void scatter_scan_k(
    const int* __restrict__ deg, const int* __restrict__ bsum,
    int* __restrict__ rowptr)
{
  __shared__ int s[256];
  const int t = threadIdx.x;
  int i = blockIdx.x * 256 + t;
  int v = (i < NN) ? deg[i] : 0;
  s[t] = v;
  __syncthreads();
  for (int off = 1; off < 256; off <<= 1) {
    int x = (t >= off) ? s[t - off] : 0;
    __syncthreads();
    s[t] += x;
    __syncthreads();
  }
  if (i < NN) rowptr[i] = bsum[blockIdx.x] + s[t] - v;
}

__global__ __launch_bounds__(256) void fill_kernel(
    const int* __restrict__ ei, const int* __restrict__ rowptr,
    int* __restrict__ cur, int* __restrict__ srcS, int* __restrict__ dstS,
    int* __restrict__ permS)
{
  int e = blockIdx.x * 256 + threadIdx.x;
  if (e >= NE) return;
  int d = ei[NE + e];
  int pos = atomicAdd(&cur[d], 1);
  int w = rowptr[d] + pos;
  srcS[w] = ei[e];
  dstS[w] = d;
  permS[w] = e;
}

// ---------------------------------------------------------------------------
// One-time, layer-invariant: eaW[w] = edge_attr[perm[w]] @ edge_w + edge_b
// (dst-sorted, bf16). MFMA over 64-edge tiles; gathers eattr via permS.
// ---------------------------------------------------------------------------
__global__ __launch_bounds__(256) void eaw_kernel(
    const float* __restrict__ eattr, const int* __restrict__ permS,
    const unsigned short* __restrict__ Bt, const float* __restrict__ bias,
    unsigned short* __restrict__ eaW)
{
  __shared__ __align__(16) unsigned short As[64 * 40];
  __shared__ __align__(16) unsigned short Bs[80 * 104];
  __shared__ float bs[80];
  const int t = threadIdx.x;
  const int e0 = blockIdx.x * 64;
  for (int i = t; i < 1040; i += 256) ((uint4*)Bs)[i] = ((const uint4*)Bt)[i];
  if (t < 80) bs[t] = (t < 66) ? bias[t] : 0.0f;
  for (int i = t; i < 1024; i += 256) {
    int r = i >> 4, j = i & 15;
    int p = permS[e0 + r];
    float2 f = ((const float2*)(eattr + (size_t)p * 32))[j];
    As[r * 40 + j * 2] = f2b(f.x);
    As[r * 40 + j * 2 + 1] = f2b(f.y);
  }
  __syncthreads();
  const int lane = t & 63, w = t >> 6, m = lane & 15, q = lane >> 4;
  f32x4 acc[5] = {};
  short8 a = *(const short8*)(As + (w * 16 + m) * 40 + q * 8);
#pragma unroll
  for (int ct = 0; ct < 5; ct++) {
    short8 b = *(const short8*)(Bs + (ct * 16 + m) * 104 + q * 8);
    acc[ct] = __builtin_amdgcn_mfma_f32_16x16x32_bf16(a, b, acc[ct], 0, 0, 0);
  }
#pragma unroll
  for (int ct = 0; ct < 5; ct++) {
    int c = ct * 16 + m;
    if (c < 66) {
      float bv = bs[c];
#pragma unroll
      for (int r2 = 0; r2 < 4; r2++) {
        int e = w * 16 + q * 4 + r2;
        eaW[(size_t)(e0 + e) * 66 + c] = f2b(acc[ct][r2] + bv);
      }
    }
  }
}

// ---------------------------------------------------------------------------
// Node-centric aggregation: block = 64 dst nodes; its CSR edge slice is a
// contiguous, coalesced range of eaW. 4 threads/edge, j = q + 4k (k<8, plus
// q==0 handles j=32). relu(eaW_e + hB[src]) accumulated straight into an LDS
// f32 accumulator via ds_add_f32; runs are block-private -> no global
// atomics, no memset, full aggr written (zero-degree rows included).
// ---------------------------------------------------------------------------
__global__ __launch_bounds__(256) void node_aggr(
    const int* __restrict__ rowptr, const int* __restrict__ srcS,
    const int* __restrict__ dstS, const unsigned int* __restrict__ eaW32,
    const unsigned int* __restrict__ hB32, float* __restrict__ aggr)
{
  __shared__ float aggrS[64 * 67];   // stride 67 keeps ds_add banks ~2-way
  __shared__ int sidx[64], didx[64];
  const int t = threadIdx.x;
  const int n0 = blockIdx.x * 64;
  const int nhi = (n0 + 64 < NN) ? (n0 + 64) : NN;
  const int eBeg = rowptr[n0];
  const int eEnd = rowptr[nhi];
  for (int i = t; i < 64 * 67; i += 256) aggrS[i] = 0.0f;
  const int el = t >> 2, q = t & 3;
  for (int c0 = eBeg; c0 < eEnd; c0 += 64) {
    __syncthreads();   // also covers aggrS init on first iteration
    if (t < 64) {
      int e = c0 + t;
      int ok = (e < eEnd) ? 1 : 0;
      sidx[t] = ok ? srcS[e] : 0;
      didx[t] = ok ? (dstS[e] - n0) : 0;
    }
    __syncthreads();
    int eg = c0 + el;
    if (eg < eEnd) {
      const unsigned int* pe = eaW32 + (size_t)eg * 33 + q;
      const unsigned int* ph = hB32 + (size_t)sidx[el] * 33 + q;
      float* ar = aggrS + didx[el] * 67;
#pragma unroll
      for (int k = 0; k < 8; k++) {
        unsigned int ua = __builtin_nontemporal_load(pe + 4 * k);
        unsigned int uh = ph[4 * k];
        int j2 = 2 * (q + 4 * k);
        float v0 = uif(ua << 16) + uif(uh << 16);
        float v1 = uif(ua & 0xffff0000u) + uif(uh & 0xffff0000u);
        atomicAdd(&ar[j2],     fmaxf(v0, 0.f));
        atomicAdd(&ar[j2 + 1], fmaxf(v1, 0.f));
      }
      if (q == 0) {   // j = 32 -> cols 64,65
        unsigned int ua = __builtin_nontemporal_load(pe + 32);
        unsigned int uh = ph[32];
        float v0 = uif(ua << 16) + uif(uh << 16);
        float v1 = uif(ua & 0xffff0000u) + uif(uh & 0xffff0000u);
        atomicAdd(&ar[64], fmaxf(v0, 0.f));
        atomicAdd(&ar[65], fmaxf(v1, 0.f));
      }
    }
  }
  __syncthreads();
  for (int i = t; i < 64 * 66; i += 256) {
    int r = i / 66, c = i - r * 66;
    int n = n0 + r;
    if (n < NN) aggr[(size_t)n * 66 + c] = aggrS[r * 67 + c];
  }
}

// ---------------------------------------------------------------------------
// Fallback (ws too small for eaW): fused MFMA message+aggregate, edge-centric.
// ---------------------------------------------------------------------------
__global__ __launch_bounds__(256) void msg_aggr2(
    const int* __restrict__ rowptr, const int* __restrict__ srcS,
    const int* __restrict__ dstS,
    const float* __restrict__ eattr, const int* __restrict__ permS,
    const unsigned short* __restrict__ Bt, const float* __restrict__ bias,
    const unsigned short* __restrict__ hB, float* __restrict__ aggr)
{
  __shared__ __align__(16) unsigned short As[64 * 40];
  __shared__ __align__(16) unsigned short Bs[80 * 104];
  __shared__ float msgS[64 * 67];
  __shared__ float bs[80];
  __shared__ int sidx[64], didx[64];
  __shared__ int runStart[65];
  __shared__ int nrunsS;
  const int t = threadIdx.x;
  const int e0 = blockIdx.x * 64;
  for (int i = t; i < 1040; i += 256) ((uint4*)Bs)[i] = ((const uint4*)Bt)[i];
  if (t < 80) bs[t] = (t < 66) ? bias[t] : 0.0f;
  if (t < 64) { sidx[t] = srcS[e0 + t]; didx[t] = dstS[e0 + t]; }
  for (int i = t; i < 1024; i += 256) {
    int r = i >> 4, j = i & 15;
    int p = permS[e0 + r];
    float2 f = ((const float2*)(eattr + (size_t)p * 32))[j];
    As[r * 40 + j * 2] = f2b(f.x);
    As[r * 40 + j * 2 + 1] = f2b(f.y);
  }
  __syncthreads();
  if (t < 64) {
    bool b = (t == 0) || (didx[t] != didx[t - 1]);
    unsigned long long mask = __ballot(b);
    int idx = __popcll(mask & ((1ull << t) - 1ull));
    if (b) runStart[idx] = t;
    if (t == 63) { nrunsS = __popcll(mask); runStart[__popcll(mask)] = 64; }
  }
  const int lane = t & 63, w = t >> 6, m = lane & 15, q = lane >> 4;
  f32x4 acc[5] = {};
  short8 a = *(const short8*)(As + (w * 16 + m) * 40 + q * 8);
#pragma unroll
  for (int ct = 0; ct < 5; ct++) {
    short8 b = *(const short8*)(Bs + (ct * 16 + m) * 104 + q * 8);
    acc[ct] = __builtin_amdgcn_mfma_f32_16x16x32_bf16(a, b, acc[ct], 0, 0, 0);
  }
#pragma unroll
  for (int ct = 0; ct < 5; ct++) {
    int c = ct * 16 + m;
    if (c < 66) {
      float bv = bs[c];
#pragma unroll
      for (int r2 = 0; r2 < 4; r2++) {
        int e = w * 16 + q * 4 + r2;
        float v = acc[ct][r2] + bv + b2f(hB[(size_t)sidx[e] * 66 + c]);
        msgS[e * 67 + c] = fmaxf(v, 0.f);
      }
    }
  }
  __syncthreads();
  const int nr = nrunsS;
  for (int task = t; task < nr * 66; task += 256) {
    int r = task / 66, c = task - r * 66;
    int s0 = runStart[r], s1 = runStart[r + 1];
    float s = 0.0f;
    for (int e = s0; e < s1; e++) s += msgS[e * 67 + c];
    int n = didx[s0];
    bool partial = false;
    if (r == 0)      partial = (rowptr[n] < e0);
    if (r == nr - 1) partial = partial || (rowptr[n + 1] > e0 + 64);
    if (partial) atomicAdd(&aggr[(size_t)n * 66 + c], s);
    else         aggr[(size_t)n * 66 + c] = s;
  }
}

// ---------------------------------------------------------------------------
// BatchNorm stats + update (fp32); bn_update also refreshes hB mirror.
// ---------------------------------------------------------------------------
__global__ __launch_bounds__(256) void bn_stats(const float* __restrict__ z,
                                                float* __restrict__ stat)
{
  const int t = threadIdx.x;
  if (t >= 198) return;
  const int c = t % 66, rs = t / 66;
  const int r0 = blockIdx.x * 1024;
  float s1 = 0.0f, s2 = 0.0f;
  int rend = r0 + 1024; if (rend > NN) rend = NN;
  for (int r = r0 + rs; r < rend; r += 3) {
    float v = z[(size_t)r * 66 + c];
    s1 += v; s2 += v * v;
  }
  atomicAdd(&stat[c], s1);
  atomicAdd(&stat[66 + c], s2);
}

__global__ __launch_bounds__(256) void bn_update(
    float* __restrict__ h, unsigned short* __restrict__ hB,
    const float* __restrict__ z, const float* __restrict__ stat,
    const float* __restrict__ gamma, const float* __restrict__ beta)
{
  int idx = blockIdx.x * 256 + threadIdx.x;
  if (idx >= NN * 66) return;
  int c = idx % 66;
  float mean = stat[c] * (1.0f / NN);
  float var  = stat[66 + c] * (1.0f / NN) - mean * mean;
  float inv  = rsqrtf(var + 1e-5f);
  float zn   = (z[idx] - mean) * inv * gamma[c] + beta[c];
  float v = 0.5f * (h[idx] + fmaxf(zn, 0.0f));
  h[idx] = v;
  hB[idx] = f2b(v);
}

// ---------------------------------------------------------------------------
// Fused edge update (block = 64 target edges), MFMA chain:
//   mid = relu(tea@W1c + b1 + P12[ts,0:66] + P12[td,66:132]);   (P12 bf16)
//   tea += 0.5*(mid@W2 + b2)
// ---------------------------------------------------------------------------
__global__ __launch_bounds__(256) void edge_fused2(
    const unsigned short* __restrict__ P12, const int* __restrict__ eli,
    const unsigned short* __restrict__ B1t, const float* __restrict__ b1,
    const unsigned short* __restrict__ B2t, const float* __restrict__ b2,
    float* __restrict__ tea)
{
  __shared__ __align__(16) unsigned short As[64 * 104];  // tea tile, then mid
  __shared__ __align__(16) unsigned short Bs1[80 * 104];
  __shared__ __align__(16) unsigned short Bs2[80 * 104];
  __shared__ float b1s[80], b2s[80];
  __shared__ int sidx[64], didx[64];
  const int t = threadIdx.x;
  const int e0 = blockIdx.x * 64;
  for (int i = t; i < 1040; i += 256) {
    ((uint4*)Bs1)[i] = ((const uint4*)B1t)[i];
    ((uint4*)Bs2)[i] = ((const uint4*)B2t)[i];
  }
  if (t < 80) { b1s[t] = (t < 66) ? b1[t] : 0.f; b2s[t] = (t < 66) ? b2[t] : 0.f; }
  if (t < 64) { sidx[t] = eli[e0 + t]; didx[t] = eli[NT + e0 + t]; }
  for (int i = t; i < 64 * 48; i += 256) {
    int r = i / 48, kk = (i - r * 48) * 2;
    unsigned short u0 = 0, u1 = 0;
    if (kk < 66) {
      float2 f = *(const float2*)(tea + (size_t)(e0 + r) * 66 + kk);
      u0 = f2b(f.x); u1 = f2b(f.y);
    }
    As[r * 104 + kk] = u0; As[r * 104 + kk + 1] = u1;
  }
  __syncthreads();
  const int lane = t & 63, w = t >> 6, m = lane & 15, q = lane >> 4;
  const unsigned short* Ap = As + (w * 16 + m) * 104 + q * 8;
  const unsigned short* Bp1 = Bs1 + m * 104 + q * 8;
  f32x4 acc[5] = {};
#pragma unroll
  for (int ks = 0; ks < 3; ks++) {
    short8 a = *(const short8*)(Ap + ks * 32);
#pragma unroll
    for (int ct = 0; ct < 5; ct++) {
      short8 b = *(const short8*)(Bp1 + ct * 16 * 104 + ks * 32);
      acc[ct] = __builtin_amdgcn_mfma_f32_16x16x32_bf16(a, b, acc[ct], 0, 0, 0);
    }
  }
  __syncthreads();  // GEMM1 reads of As done before mid overwrite
#pragma unroll
  for (int ct = 0; ct < 5; ct++) {
    int c = ct * 16 + m;
    if (c < 66) {
      float bv = b1s[c];
#pragma unroll
      for (int r2 = 0; r2 < 4; r2++) {
        int e = w * 16 + q * 4 + r2;
        float v = acc[ct][r2] + bv + b2f(P12[(size_t)sidx[e] * 132 + c])
                                   + b2f(P12[(size_t)didx[e] * 132 + 66 + c]);
        As[e * 104 + c] = f2b(fmaxf(v, 0.f));
      }
    }
  }
  __syncthreads();
  const unsigned short* Bp2 = Bs2 + m * 104 + q * 8;
  f32x4 acc2[5] = {};
#pragma unroll
  for (int ks = 0; ks < 3; ks++) {
    short8 a = *(const short8*)(Ap + ks * 32);
#pragma unroll
    for (int ct = 0; ct < 5; ct++) {
      short8 b = *(const short8*)(Bp2 + ct * 16 * 104 + ks * 32);
      acc2[ct] = __builtin_amdgcn_mfma_f32_16x16x32_bf16(a, b, acc2[ct], 0, 0, 0);
    }
  }
#pragma unroll
  for (int ct = 0; ct < 5; ct++) {
    int c = ct * 16 + m;
    if (c < 66) {
      float bv = b2s[c];
#pragma unroll
      for (int r2 = 0; r2 < 4; r2++) {
        int e = w * 16 + q * 4 + r2;
        size_t idx = (size_t)(e0 + e) * 66 + c;
        tea[idx] += 0.5f * (acc2[ct][r2] + bv);
      }
    }
  }
}

// ---------------------------------------------------------------------------
// Fused final classifier (block = 64 target edges):
//   o1 = relu(tea@mw1c + b1 + P12f[ts,0:50] + P12f[td,50:100]);  (P12f bf16)
//   o2 = relu(o1@w2+b2); out = o2@w3+b3
// ---------------------------------------------------------------------------
__global__ __launch_bounds__(256) void final_fused2(
    const float* __restrict__ tea, const unsigned short* __restrict__ P12f,
    const int* __restrict__ eli, const unsigned short* __restrict__ B1t,
    const float* __restrict__ b1, const float* __restrict__ w2,
    const float* __restrict__ b2, const float* __restrict__ w3,
    const float* __restrict__ b3, float* __restrict__ out)
{
  __shared__ __align__(16) unsigned short As[64 * 104];
  __shared__ __align__(16) unsigned short Bs[64 * 104];
  __shared__ float o1s[64 * 51];
  __shared__ float o2s[64 * 25];
  __shared__ float w2s[50 * 25], w3s[50];
  __shared__ float b1s[64], b2s[25], b3s[2];
  __shared__ int sidx[64], didx[64];
  const int t = threadIdx.x;
  const int e0 = blockIdx.x * 64;
  for (int i = t; i < 832; i += 256) ((uint4*)Bs)[i] = ((const uint4*)B1t)[i];
  for (int i = t; i < 50 * 25; i += 256) w2s[i] = w2[i];
  if (t < 50) w3s[t] = w3[t];
  if (t < 64) { b1s[t] = (t < 50) ? b1[t] : 0.f; sidx[t] = eli[e0 + t]; didx[t] = eli[NT + e0 + t]; }
  if (t < 25) b2s[t] = b2[t];
  if (t < 2)  b3s[t] = b3[t];
  for (int i = t; i < 64 * 48; i += 256) {
    int r = i / 48, kk = (i - r * 48) * 2;
    unsigned short u0 = 0, u1 = 0;
    if (kk < 66) {
      float2 f = *(const float2*)(tea + (size_t)(e0 + r) * 66 + kk);
      u0 = f2b(f.x); u1 = f2b(f.y);
    }
    As[r * 104 + kk] = u0; As[r * 104 + kk + 1] = u1;
  }
  __syncthreads();
  const int lane = t & 63, w = t >> 6, m = lane & 15, q = lane >> 4;
  const unsigned short* Ap = As + (w * 16 + m) * 104 + q * 8;
  const unsigned short* Bp = Bs + m * 104 + q * 8;
  f32x4 acc[4] = {};
#pragma unroll
  for (int ks = 0; ks < 3; ks++) {
    short8 a = *(const short8*)(Ap + ks * 32);
#pragma unroll
    for (int ct = 0; ct < 4; ct++) {
      short8 b = *(const short8*)(Bp + ct * 16 * 104 + ks * 32);
      acc[ct] = __builtin_amdgcn_mfma_f32_16x16x32_bf16(a, b, acc[ct], 0, 0, 0);
    }
  }
#pragma unroll
  for (int ct = 0; ct < 4; ct++) {
    int c = ct * 16 + m;
    if (c < 50) {
      float bv = b1s[c];
#pragma unroll
      for (int r2 = 0; r2 < 4; r2++) {
        int e = w * 16 + q * 4 + r2;
        float v = acc[ct][r2] + bv + b2f(P12f[(size_t)sidx[e] * 100 + c])
                                   + b2f(P12f[(size_t)didx[e] * 100 + 50 + c]);
        o1s[e * 51 + c] = fmaxf(v, 0.f);
      }
    }
  }
  __syncthreads();
  for (int it = t; it < 64 * 25; it += 256) {
    int e = it / 25, c = it - e * 25;
    float s = b2s[c];
    for (int k = 0; k < 50; k++) s = fmaf(o1s[e * 51 + k], w2s[k * 25 + c], s);
    o2s[e * 25 + c] = fmaxf(s, 0.f);
  }
  __syncthreads();
  if (t < 128) {
    int e = t >> 1, c = t & 1;
    float s = b3s[c];
    for (int k = 0; k < 25; k++) s = fmaf(o2s[e * 25 + k], w3s[k * 2 + c], s);
    out[(size_t)(e0 + e) * 2 + c] = s;
  }
}

// ---------------------------------------------------------------------------
extern "C" void kernel_launch(void* const* d_in, const int* in_sizes, int n_in,
                              void* d_out, int out_size, void* d_ws, size_t ws_size,
                              hipStream_t stream) {
  const float* x      = (const float*)d_in[0];
  const int*   ei     = (const int*)  d_in[1];
  const float* eattr  = (const float*)d_in[2];
  const int*   eli    = (const int*)  d_in[3];
  const float* tattr  = (const float*)d_in[4];
  const float* node_w = (const float*)d_in[5];
  const float* node_b = (const float*)d_in[6];
  const float* edge_w = (const float*)d_in[7];
  const float* edge_b = (const float*)d_in[8];
  const float* cw1    = (const float*)d_in[9];
  const float* cb1    = (const float*)d_in[10];
  const float* cw2    = (const float*)d_in[11];
  const float* cb2    = (const float*)d_in[12];
  const float* bng    = (const float*)d_in[13];
  const float* bnb    = (const float*)d_in[14];
  const float* ew1    = (const float*)d_in[15];
  const float* eb1    = (const float*)d_in[16];
  const float* ew2    = (const float*)d_in[17];
  const float* eb2    = (const float*)d_in[18];
  const float* mw1    = (const float*)d_in[19];
  const float* mb1    = (const float*)d_in[20];
  const float* mw2    = (const float*)d_in[21];
  const float* mb2    = (const float*)d_in[22];
  const float* mw3    = (const float*)d_in[23];
  const float* mb3    = (const float*)d_in[24];
  float* out = (float*)d_out;

  // ---- workspace layout (optional eaW last) ----
  char* p = (char*)d_ws;
  auto alloc = [&](size_t bytes) { void* r = p; p += (bytes + 255) & ~(size_t)255; return r; };
  float* h      = (float*)alloc((size_t)NN * 66 * 4);
  unsigned short* hB = (unsigned short*)alloc((size_t)NN * 66 * 2);
  float* big    = (float*)alloc((size_t)NN * 132 * 4);  // P12(bf16) / midb
  float* zbuf   = (float*)alloc((size_t)NN * 66 * 4);   // aggr / z
  float* tea    = (float*)alloc((size_t)NT * 66 * 4);
  float* stat   = (float*)alloc(1024);
  int*   rowptr = (int*)alloc((NN + 1) * 4);
  int*   cur    = (int*)alloc((size_t)NN * 4);
  int*   bsum   = (int*)alloc((SCB + 1) * 4);
  int*   srcS   = (int*)alloc((size_t)NE * 4);
  int*   dstS   = (int*)alloc((size_t)NE * 4);
  int*   permS  = (int*)alloc((size_t)NE * 4);
  unsigned short* wT = (unsigned short*)alloc((size_t)140000 * 2);
  size_t used = (size_t)(p - (char*)d_ws);
  unsigned short* eaW = nullptr;
  if (ws_size >= used + (size_t)NE * 66 * 2 + 256)
    eaW = (unsigned short*)alloc((size_t)NE * 66 * 2);

  const int gN = (NN + 63) / 64;  // 1563
  const int gT = NT / 64;         // 3125
  const int gE = NE / 64;         // 15625

  // ---- CSR build ----
  hipMemsetAsync(cur, 0, (size_t)NN * sizeof(int), stream);
  hist_kernel<<<(NE + 255) / 256, 256, 0, stream>>>(ei, cur);
  blocksum_k<<<SCB, 256, 0, stream>>>(cur, bsum);
  scansums_k<<<1, 512, 0, stream>>>(bsum, rowptr);
  scatter_scan_k<<<SCB, 256, 0, stream>>>(cur, bsum, rowptr);
  hipMemsetAsync(cur, 0, (size_t)NN * sizeof(int), stream);
  fill_kernel<<<(NE + 255) / 256, 256, 0, stream>>>(ei, rowptr, cur, srcS, dstS, permS);

  // ---- weight prep ----
  PrepTab tb;
  int offs[14];
  int off = 0;
  auto set = [&](int s, const float* A, const float* B, int K, int C, int rows) {
    tb.a[s] = A; tb.b[s] = B; tb.K[s] = K; tb.C[s] = C; tb.rows[s] = rows;
    tb.off[s] = off; offs[s] = off; off += rows * 104;
  };
  set(0, node_w, nullptr, 64, 66, 80);
  set(1, edge_w, nullptr, 32, 66, 80);
  for (int l = 0; l < 2; l++) {
    set(2 + l, cw1 + (size_t)l * 4356, nullptr, 66, 66, 80);
    set(4 + l, cw2 + (size_t)l * 4356, nullptr, 66, 66, 80);
    set(6 + l, ew1 + (size_t)l * 13068 + 8712, nullptr, 66, 66, 80);       // W1c
    set(8 + l, ew2 + (size_t)l * 4356, nullptr, 66, 66, 80);
    set(10 + l, ew1 + (size_t)l * 13068, ew1 + (size_t)l * 13068 + 4356,   // W1a||W1b
        66, 66, 144);
  }
  set(12, mw1, mw1 + 3300, 66, 50, 112);   // A||B
  set(13, mw1 + 6600, nullptr, 66, 50, 80);  // C
  prep_w<<<14, 256, 0, stream>>>(tb, wT);

  // ---- one-time, layer-invariant ea projection (direct permS gather) ----
  if (eaW)
    eaw_kernel<<<gE, 256, 0, stream>>>(eattr, permS, wT + offs[1], edge_b, eaW);

  // ---- embeds ----
  mfma_gemm<64, 2, 5, 66, 0, 4><<<gN, 256, 0, stream>>>(
      x, nullptr, wT + offs[0], node_b, h, hB, NN);
  mfma_gemm<32, 1, 5, 66, 0, 0><<<gT, 256, 0, stream>>>(
      tattr, nullptr, wT + offs[1], edge_b, tea, nullptr, NT);

  for (int l = 0; l < 2; l++) {
    // aggregation
    if (eaW) {
      node_aggr<<<gN, 256, 0, stream>>>(rowptr, srcS, dstS,
                                        (const unsigned int*)eaW,
                                        (const unsigned int*)hB, zbuf);
    } else {
      hipMemsetAsync(zbuf, 0, (size_t)NN * 66 * sizeof(float), stream);
      msg_aggr2<<<gE, 256, 0, stream>>>(rowptr, srcS, dstS, eattr, permS,
                                        wT + offs[1], edge_b, hB, zbuf);
    }
    // node MLP: midb = bf16(relu((h+aggr)@cw1+b1)); z = midb@cw2+b2
    mfma_gemm<66, 3, 5, 66, 1, 3><<<gN, 256, 0, stream>>>(
        h, zbuf, wT + offs[2 + l], cb1 + l * 66, (unsigned short*)big, nullptr, NN);
    mfma_gemm<66, 3, 5, 66, 3, 0><<<gN, 256, 0, stream>>>(
        (unsigned short*)big, nullptr, wT + offs[4 + l], cb2 + l * 66, zbuf, nullptr, NN);
    // batchnorm + h update (refreshes hB mirror)
    hipMemsetAsync(stat, 0, 132 * sizeof(float), stream);
    bn_stats<<<(NN + 1023) / 1024, 256, 0, stream>>>(zbuf, stat);
    bn_update<<<(NN * 66 + 255) / 256, 256, 0, stream>>>(h, hB, zbuf, stat,
                                                         bng + l * 66, bnb + l * 66);
    // edge update: P12 = bf16(h @ [W1a||W1b]), then fused tile kernel
    mfma_gemm<66, 3, 9, 132, 0, 2><<<gN, 256, 0, stream>>>(
        h, nullptr, wT + offs[10 + l], nullptr, big, nullptr, NN);
    edge_fused2<<<gT, 256, 0, stream>>>((const unsigned short*)big, eli,
                                        wT + offs[6 + l], eb1 + l * 66,
                                        wT + offs[8 + l], eb2 + l * 66, tea);
  }

  // ---- final classifier ----
  mfma_gemm<66, 3, 7, 100, 2, 2><<<gN, 256, 0, stream>>>(
      h, nullptr, wT + offs[12], nullptr, big, nullptr, NN);
  final_fused2<<<gT, 256, 0, stream>>>(tea, (const unsigned short*)big, eli,
                                       wT + offs[13], mb1,
                                       mw2, mb2, mw3, mb3, out);
}

// Round 3
// 1802.930 us; speedup vs baseline: 1.0443x; 1.0443x over previous
//
#include <hip/hip_runtime.h>

#define NN 100000   // nodes
#define NE 1000000  // edges (divisible by 64)
#define NT 200000   // target edges (divisible by 64)
#define SCB 391     // ceil(NN/256) scan blocks

typedef __attribute__((ext_vector_type(8))) short short8;
typedef __attribute__((ext_vector_type(4))) float f32x4;

__device__ __forceinline__ unsigned short f2b(float x) {  // fp32 -> bf16 RNE
  union { float f; unsigned int u; } v; v.f = x;
  unsigned int r = v.u + 0x7fffu + ((v.u >> 16) & 1u);
  return (unsigned short)(r >> 16);
}
__device__ __forceinline__ float b2f(unsigned short x) {
  union { unsigned int u; float f; } v; v.u = ((unsigned int)x) << 16;
  return v.f;
}
__device__ __forceinline__ float uif(unsigned int u) {
  union { unsigned int u; float f; } v; v.u = u; return v.f;
}

// ---------------------------------------------------------------------------
// Weight prep: up to two fp32 sources [K][C] -> bf16 transposed tile
// [rows][104]; row c<C from A col c, C<=c<2C from B col c-C, rest zero.
// ---------------------------------------------------------------------------
struct PrepTab {
  const float* a[14]; const float* b[14];
  int K[14], C[14], rows[14], off[14];
};

__global__ __launch_bounds__(256) void prep_w(PrepTab tab, unsigned short* wT) {
  int s = blockIdx.x;
  const float* A = tab.a[s];
  const float* B = tab.b[s];
  int K = tab.K[s], C = tab.C[s], rows = tab.rows[s];
  unsigned short* dst = wT + tab.off[s];
  int n = rows * 104;
  for (int i = threadIdx.x; i < n; i += 256) {
    int c = i / 104, k = i - c * 104;
    float v = 0.0f;
    if (k < K) {
      if (c < C) v = A[k * C + c];
      else if (B && c < 2 * C) v = B[k * C + (c - C)];
    }
    dst[i] = f2b(v);
  }
}

// ---------------------------------------------------------------------------
// Generic MFMA row-GEMM: out[R,C] = act(in (+add)) @ W + bias
// AIN: 0=f32, 1=f32+add, 2=relu(f32), 3=bf16 input.
// ROUT bit0=relu, bit1=bf16 out, bit2=also write bf16 mirror to out2.
// ---------------------------------------------------------------------------
template<int K, int KSTEPS, int CT, int C, int AIN, int ROUT>
__global__ __launch_bounds__(256) void mfma_gemm(
    const void* __restrict__ in, const float* __restrict__ add,
    const unsigned short* __restrict__ Bt, const float* __restrict__ bias,
    void* __restrict__ outp, void* __restrict__ out2, int R)
{
  constexpr int CR = CT * 16;
  __shared__ __align__(16) unsigned short As[64 * 104];
  __shared__ __align__(16) unsigned short Bs[CR * 104];
  __shared__ float bs[CR];
  const int t = threadIdx.x;
  const int r0 = blockIdx.x * 64;
  for (int i = t; i < CT * 208; i += 256) ((uint4*)Bs)[i] = ((const uint4*)Bt)[i];
  if (t < CR) bs[t] = (bias && t < C) ? bias[t] : 0.0f;
  constexpr int KH = KSTEPS * 16;  // float2 slots per row
  for (int i = t; i < 64 * KH; i += 256) {
    int r = i / KH, kk = (i - r * KH) * 2;
    int rg = r0 + r;
    unsigned short u0 = 0, u1 = 0;
    if (rg < R && kk < K) {
      if constexpr (AIN == 3) {
        unsigned int u = ((const unsigned int*)in)[((size_t)rg * K + kk) >> 1];
        u0 = u & 0xffffu; u1 = u >> 16;
      } else {
        float2 f = *(const float2*)((const float*)in + (size_t)rg * K + kk);
        float v0 = f.x, v1 = f.y;
        if constexpr (AIN == 1) {
          float2 g = *(const float2*)(add + (size_t)rg * K + kk);
          v0 += g.x; v1 += g.y;
        }
        if constexpr (AIN == 2) { v0 = fmaxf(v0, 0.f); v1 = fmaxf(v1, 0.f); }
        u0 = f2b(v0); u1 = f2b(v1);
      }
    }
    As[r * 104 + kk] = u0; As[r * 104 + kk + 1] = u1;
  }
  __syncthreads();
  const int lane = t & 63, w = t >> 6, m = lane & 15, q = lane >> 4;
  f32x4 acc[CT] = {};
  const unsigned short* Ap = As + (w * 16 + m) * 104 + q * 8;
  const unsigned short* Bp = Bs + m * 104 + q * 8;
#pragma unroll
  for (int ks = 0; ks < KSTEPS; ks++) {
    short8 a = *(const short8*)(Ap + ks * 32);
#pragma unroll
    for (int ct = 0; ct < CT; ct++) {
      short8 b = *(const short8*)(Bp + ct * 16 * 104 + ks * 32);
      acc[ct] = __builtin_amdgcn_mfma_f32_16x16x32_bf16(a, b, acc[ct], 0, 0, 0);
    }
  }
#pragma unroll
  for (int ct = 0; ct < CT; ct++) {
    int c = ct * 16 + m;
    if (c < C) {
      float bv = bs[c];
#pragma unroll
      for (int r2 = 0; r2 < 4; r2++) {
        int row = r0 + w * 16 + q * 4 + r2;
        if (row < R) {
          float v = acc[ct][r2] + bv;
          if constexpr ((ROUT & 1) != 0) v = fmaxf(v, 0.f);
          if constexpr ((ROUT & 2) != 0)
            ((unsigned short*)outp)[(size_t)row * C + c] = f2b(v);
          else
            ((float*)outp)[(size_t)row * C + c] = v;
          if constexpr ((ROUT & 4) != 0)
            ((unsigned short*)out2)[(size_t)row * C + c] = f2b(v);
        }
      }
    }
  }
}

// ---------------------------------------------------------------------------
// CSR build: histogram + 3-pass coalesced scan + fill
// ---------------------------------------------------------------------------
__global__ __launch_bounds__(256) void hist_kernel(const int* __restrict__ ei,
                                                   int* __restrict__ deg)
{
  int e = blockIdx.x * 256 + threadIdx.x;
  if (e < NE) atomicAdd(&deg[ei[NE + e]], 1);
}

__global__ __launch_bounds__(256) void blocksum_k(const int* __restrict__ deg,
                                                  int* __restrict__ bsum)
{
  __shared__ int red[256];
  const int t = threadIdx.x;
  int i = blockIdx.x * 256 + t;
  red[t] = (i < NN) ? deg[i] : 0;
  __syncthreads();
  for (int s = 128; s > 0; s >>= 1) {
    if (t < s) red[t] += red[t + s];
    __syncthreads();
  }
  if (t == 0) bsum[blockIdx.x] = red[0];
}

__global__ __launch_bounds__(512) void scansums_k(int* __restrict__ bsum,
                                                  int* __restrict__ rowptr)
{
  __shared__ int s[512];
  const int t = threadIdx.x;
  s[t] = (t < SCB) ? bsum[t] : 0;
  __syncthreads();
  for (int off = 1; off < 512; off <<= 1) {
    int v = (t >= off) ? s[t - off] : 0;
    __syncthreads();
    s[t] += v;
    __syncthreads();
  }
  if (t < SCB) bsum[t] = (t == 0) ? 0 : s[t - 1];  // exclusive
  if (t == 0) rowptr[NN] = NE;
}

__global__ __launch_bounds__(256) void scatter_scan_k(
    const int* __restrict__ deg, const int* __restrict__ bsum,
    int* __restrict__ rowptr)
{
  __shared__ int s[256];
  const int t = threadIdx.x;
  int i = blockIdx.x * 256 + t;
  int v = (i < NN) ? deg[i] : 0;
  s[t] = v;
  __syncthreads();
  for (int off = 1; off < 256; off <<= 1) {
    int x = (t >= off) ? s[t - off] : 0;
    __syncthreads();
    s[t] += x;
    __syncthreads();
  }
  if (i < NN) rowptr[i] = bsum[blockIdx.x] + s[t] - v;
}

__global__ __launch_bounds__(256) void fill_kernel(
    const int* __restrict__ ei, const int* __restrict__ rowptr,
    int* __restrict__ cur, int* __restrict__ srcS, int* __restrict__ dstS,
    int* __restrict__ permS)
{
  int e = blockIdx.x * 256 + threadIdx.x;
  if (e >= NE) return;
  int d = ei[NE + e];
  int pos = atomicAdd(&cur[d], 1);
  int w = rowptr[d] + pos;
  srcS[w] = ei[e];
  dstS[w] = d;
  permS[w] = e;
}

// ---------------------------------------------------------------------------
// One-time, layer-invariant: eaW[w] = edge_attr[perm[w]] @ edge_w + edge_b
// (dst-sorted, bf16). MFMA over 64-edge tiles; gathers eattr via permS.
// ---------------------------------------------------------------------------
__global__ __launch_bounds__(256) void eaw_kernel(
    const float* __restrict__ eattr, const int* __restrict__ permS,
    const unsigned short* __restrict__ Bt, const float* __restrict__ bias,
    unsigned short* __restrict__ eaW)
{
  __shared__ __align__(16) unsigned short As[64 * 40];
  __shared__ __align__(16) unsigned short Bs[80 * 104];
  __shared__ float bs[80];
  const int t = threadIdx.x;
  const int e0 = blockIdx.x * 64;
  for (int i = t; i < 1040; i += 256) ((uint4*)Bs)[i] = ((const uint4*)Bt)[i];
  if (t < 80) bs[t] = (t < 66) ? bias[t] : 0.0f;
  for (int i = t; i < 1024; i += 256) {
    int r = i >> 4, j = i & 15;
    int p = permS[e0 + r];
    float2 f = ((const float2*)(eattr + (size_t)p * 32))[j];
    As[r * 40 + j * 2] = f2b(f.x);
    As[r * 40 + j * 2 + 1] = f2b(f.y);
  }
  __syncthreads();
  const int lane = t & 63, w = t >> 6, m = lane & 15, q = lane >> 4;
  f32x4 acc[5] = {};
  short8 a = *(const short8*)(As + (w * 16 + m) * 40 + q * 8);
#pragma unroll
  for (int ct = 0; ct < 5; ct++) {
    short8 b = *(const short8*)(Bs + (ct * 16 + m) * 104 + q * 8);
    acc[ct] = __builtin_amdgcn_mfma_f32_16x16x32_bf16(a, b, acc[ct], 0, 0, 0);
  }
#pragma unroll
  for (int ct = 0; ct < 5; ct++) {
    int c = ct * 16 + m;
    if (c < 66) {
      float bv = bs[c];
#pragma unroll
      for (int r2 = 0; r2 < 4; r2++) {
        int e = w * 16 + q * 4 + r2;
        eaW[(size_t)(e0 + e) * 66 + c] = f2b(acc[ct][r2] + bv);
      }
    }
  }
}

// ---------------------------------------------------------------------------
// Edge-centric aggregation v4: block = 64 dst-sorted edges (coalesced eaW
// slice, whole-row hB gathers). Per-edge run id from ballot (rid = count of
// boundaries at positions <= t, minus 1); relu(ea+h) accumulated directly
// into per-run LDS accumulators via ds_add_f32 (no msgS round-trip, no
// serial segmented sum). Writeback: one value per (run, col); partial
// first/last runs via global atomicAdd.
// ---------------------------------------------------------------------------
__global__ __launch_bounds__(256) void msg_aggr4(
    const int* __restrict__ rowptr, const int* __restrict__ srcS,
    const int* __restrict__ dstS, const unsigned int* __restrict__ eaW32,
    const unsigned int* __restrict__ hB32, float* __restrict__ aggr)
{
  __shared__ float accS[64 * 67];   // per-run accumulators, stride 67
  __shared__ int sidx[80], rid[80]; // padded: guard compiler-speculated reads
  __shared__ int didx[64];
  __shared__ int runStart[65];
  __shared__ int nrunsS;
  const int t = threadIdx.x;
  const int e0 = blockIdx.x * 64;
  if (t < 64) {
    int sv = srcS[e0 + t];
    int dv = dstS[e0 + t];
    sidx[t] = sv;
    didx[t] = dv;
    int dprev = __shfl_up(dv, 1);           // no LDS dependence
    bool b = (t == 0) || (dv != dprev);
    unsigned long long mask = __ballot(b);
    int below = __popcll(mask & ((1ull << t) - 1ull));
    rid[t] = b ? below : below - 1;         // run index of edge t
    if (b) runStart[below] = t;
    if (t == 63) { nrunsS = __popcll(mask); runStart[__popcll(mask)] = 64; }
  }
  __syncthreads();
  const int nr = nrunsS;
  for (int i = t; i < nr * 67; i += 256) accS[i] = 0.0f;
  __syncthreads();
  // phase A: 2112 u32 elements (64 edges x 33), fully coalesced eaW stream.
  const unsigned int* ea = eaW32 + (size_t)e0 * 33;
  int idx = t, e = t / 33, j = t - (t / 33) * 33;
#pragma unroll
  for (int it = 0; it < 9; it++) {
    if (idx < 2112) {
      unsigned int ua = ea[idx];
      unsigned int uh = hB32[(size_t)sidx[e] * 33 + j];
      float v0 = fmaxf(uif(ua << 16) + uif(uh << 16), 0.f);
      float v1 = fmaxf(uif(ua & 0xffff0000u) + uif(uh & 0xffff0000u), 0.f);
      float* ar = accS + rid[e] * 67 + 2 * j;
      atomicAdd(ar, v0);
      atomicAdd(ar + 1, v1);
    }
    idx += 256; e += 7; j += 25;
    if (j >= 33) { j -= 33; e++; }
  }
  __syncthreads();
  // writeback
  for (int task = t; task < nr * 66; task += 256) {
    int r = task / 66, c = task - r * 66;
    float s = accS[r * 67 + c];
    int n = didx[runStart[r]];
    bool partial = false;
    if (r == 0)      partial = (rowptr[n] < e0);
    if (r == nr - 1) partial = partial || (rowptr[n + 1] > e0 + 64);
    if (partial) atomicAdd(&aggr[(size_t)n * 66 + c], s);
    else         aggr[(size_t)n * 66 + c] = s;
  }
}

// ---------------------------------------------------------------------------
// Fallback (ws too small for eaW): fused MFMA message+aggregate, edge-centric.
// ---------------------------------------------------------------------------
__global__ __launch_bounds__(256) void msg_aggr2(
    const int* __restrict__ rowptr, const int* __restrict__ srcS,
    const int* __restrict__ dstS,
    const float* __restrict__ eattr, const int* __restrict__ permS,
    const unsigned short* __restrict__ Bt, const float* __restrict__ bias,
    const unsigned short* __restrict__ hB, float* __restrict__ aggr)
{
  __shared__ __align__(16) unsigned short As[64 * 40];
  __shared__ __align__(16) unsigned short Bs[80 * 104];
  __shared__ float msgS[64 * 67];
  __shared__ float bs[80];
  __shared__ int sidx[64], didx[64];
  __shared__ int runStart[65];
  __shared__ int nrunsS;
  const int t = threadIdx.x;
  const int e0 = blockIdx.x * 64;
  for (int i = t; i < 1040; i += 256) ((uint4*)Bs)[i] = ((const uint4*)Bt)[i];
  if (t < 80) bs[t] = (t < 66) ? bias[t] : 0.0f;
  if (t < 64) { sidx[t] = srcS[e0 + t]; didx[t] = dstS[e0 + t]; }
  for (int i = t; i < 1024; i += 256) {
    int r = i >> 4, j = i & 15;
    int p = permS[e0 + r];
    float2 f = ((const float2*)(eattr + (size_t)p * 32))[j];
    As[r * 40 + j * 2] = f2b(f.x);
    As[r * 40 + j * 2 + 1] = f2b(f.y);
  }
  __syncthreads();
  if (t < 64) {
    bool b = (t == 0) || (didx[t] != didx[t - 1]);
    unsigned long long mask = __ballot(b);
    int idx = __popcll(mask & ((1ull << t) - 1ull));
    if (b) runStart[idx] = t;
    if (t == 63) { nrunsS = __popcll(mask); runStart[__popcll(mask)] = 64; }
  }
  const int lane = t & 63, w = t >> 6, m = lane & 15, q = lane >> 4;
  f32x4 acc[5] = {};
  short8 a = *(const short8*)(As + (w * 16 + m) * 40 + q * 8);
#pragma unroll
  for (int ct = 0; ct < 5; ct++) {
    short8 b = *(const short8*)(Bs + (ct * 16 + m) * 104 + q * 8);
    acc[ct] = __builtin_amdgcn_mfma_f32_16x16x32_bf16(a, b, acc[ct], 0, 0, 0);
  }
#pragma unroll
  for (int ct = 0; ct < 5; ct++) {
    int c = ct * 16 + m;
    if (c < 66) {
      float bv = bs[c];
#pragma unroll
      for (int r2 = 0; r2 < 4; r2++) {
        int e = w * 16 + q * 4 + r2;
        float v = acc[ct][r2] + bv + b2f(hB[(size_t)sidx[e] * 66 + c]);
        msgS[e * 67 + c] = fmaxf(v, 0.f);
      }
    }
  }
  __syncthreads();
  const int nr = nrunsS;
  for (int task = t; task < nr * 66; task += 256) {
    int r = task / 66, c = task - r * 66;
    int s0 = runStart[r], s1 = runStart[r + 1];
    float s = 0.0f;
    for (int e = s0; e < s1; e++) s += msgS[e * 67 + c];
    int n = didx[s0];
    bool partial = false;
    if (r == 0)      partial = (rowptr[n] < e0);
    if (r == nr - 1) partial = partial || (rowptr[n + 1] > e0 + 64);
    if (partial) atomicAdd(&aggr[(size_t)n * 66 + c], s);
    else         aggr[(size_t)n * 66 + c] = s;
  }
}

// ---------------------------------------------------------------------------
// BatchNorm stats + update (fp32); bn_update also refreshes hB mirror.
// ---------------------------------------------------------------------------
__global__ __launch_bounds__(256) void bn_stats(const float* __restrict__ z,
                                                float* __restrict__ stat)
{
  const int t = threadIdx.x;
  if (t >= 198) return;
  const int c = t % 66, rs = t / 66;
  const int r0 = blockIdx.x * 1024;
  float s1 = 0.0f, s2 = 0.0f;
  int rend = r0 + 1024; if (rend > NN) rend = NN;
  for (int r = r0 + rs; r < rend; r += 3) {
    float v = z[(size_t)r * 66 + c];
    s1 += v; s2 += v * v;
  }
  atomicAdd(&stat[c], s1);
  atomicAdd(&stat[66 + c], s2);
}

__global__ __launch_bounds__(256) void bn_update(
    float* __restrict__ h, unsigned short* __restrict__ hB,
    const float* __restrict__ z, const float* __restrict__ stat,
    const float* __restrict__ gamma, const float* __restrict__ beta)
{
  int idx = blockIdx.x * 256 + threadIdx.x;
  if (idx >= NN * 66) return;
  int c = idx % 66;
  float mean = stat[c] * (1.0f / NN);
  float var  = stat[66 + c] * (1.0f / NN) - mean * mean;
  float inv  = rsqrtf(var + 1e-5f);
  float zn   = (z[idx] - mean) * inv * gamma[c] + beta[c];
  float v = 0.5f * (h[idx] + fmaxf(zn, 0.0f));
  h[idx] = v;
  hB[idx] = f2b(v);
}

// ---------------------------------------------------------------------------
// Fused edge update (block = 64 target edges), MFMA chain:
//   mid = relu(tea@W1c + b1 + P12[ts,0:66] + P12[td,66:132]);   (P12 bf16)
//   tea += 0.5*(mid@W2 + b2)
// ---------------------------------------------------------------------------
__global__ __launch_bounds__(256) void edge_fused2(
    const unsigned short* __restrict__ P12, const int* __restrict__ eli,
    const unsigned short* __restrict__ B1t, const float* __restrict__ b1,
    const unsigned short* __restrict__ B2t, const float* __restrict__ b2,
    float* __restrict__ tea)
{
  __shared__ __align__(16) unsigned short As[64 * 104];  // tea tile, then mid
  __shared__ __align__(16) unsigned short Bs1[80 * 104];
  __shared__ __align__(16) unsigned short Bs2[80 * 104];
  __shared__ float b1s[80], b2s[80];
  __shared__ int sidx[64], didx[64];
  const int t = threadIdx.x;
  const int e0 = blockIdx.x * 64;
  for (int i = t; i < 1040; i += 256) {
    ((uint4*)Bs1)[i] = ((const uint4*)B1t)[i];
    ((uint4*)Bs2)[i] = ((const uint4*)B2t)[i];
  }
  if (t < 80) { b1s[t] = (t < 66) ? b1[t] : 0.f; b2s[t] = (t < 66) ? b2[t] : 0.f; }
  if (t < 64) { sidx[t] = eli[e0 + t]; didx[t] = eli[NT + e0 + t]; }
  for (int i = t; i < 64 * 48; i += 256) {
    int r = i / 48, kk = (i - r * 48) * 2;
    unsigned short u0 = 0, u1 = 0;
    if (kk < 66) {
      float2 f = *(const float2*)(tea + (size_t)(e0 + r) * 66 + kk);
      u0 = f2b(f.x); u1 = f2b(f.y);
    }
    As[r * 104 + kk] = u0; As[r * 104 + kk + 1] = u1;
  }
  __syncthreads();
  const int lane = t & 63, w = t >> 6, m = lane & 15, q = lane >> 4;
  const unsigned short* Ap = As + (w * 16 + m) * 104 + q * 8;
  const unsigned short* Bp1 = Bs1 + m * 104 + q * 8;
  f32x4 acc[5] = {};
#pragma unroll
  for (int ks = 0; ks < 3; ks++) {
    short8 a = *(const short8*)(Ap + ks * 32);
#pragma unroll
    for (int ct = 0; ct < 5; ct++) {
      short8 b = *(const short8*)(Bp1 + ct * 16 * 104 + ks * 32);
      acc[ct] = __builtin_amdgcn_mfma_f32_16x16x32_bf16(a, b, acc[ct], 0, 0, 0);
    }
  }
  __syncthreads();  // GEMM1 reads of As done before mid overwrite
#pragma unroll
  for (int ct = 0; ct < 5; ct++) {
    int c = ct * 16 + m;
    if (c < 66) {
      float bv = b1s[c];
#pragma unroll
      for (int r2 = 0; r2 < 4; r2++) {
        int e = w * 16 + q * 4 + r2;
        float v = acc[ct][r2] + bv + b2f(P12[(size_t)sidx[e] * 132 + c])
                                   + b2f(P12[(size_t)didx[e] * 132 + 66 + c]);
        As[e * 104 + c] = f2b(fmaxf(v, 0.f));
      }
    }
  }
  __syncthreads();
  const unsigned short* Bp2 = Bs2 + m * 104 + q * 8;
  f32x4 acc2[5] = {};
#pragma unroll
  for (int ks = 0; ks < 3; ks++) {
    short8 a = *(const short8*)(Ap + ks * 32);
#pragma unroll
    for (int ct = 0; ct < 5; ct++) {
      short8 b = *(const short8*)(Bp2 + ct * 16 * 104 + ks * 32);
      acc2[ct] = __builtin_amdgcn_mfma_f32_16x16x32_bf16(a, b, acc2[ct], 0, 0, 0);
    }
  }
#pragma unroll
  for (int ct = 0; ct < 5; ct++) {
    int c = ct * 16 + m;
    if (c < 66) {
      float bv = b2s[c];
#pragma unroll
      for (int r2 = 0; r2 < 4; r2++) {
        int e = w * 16 + q * 4 + r2;
        size_t idx = (size_t)(e0 + e) * 66 + c;
        tea[idx] += 0.5f * (acc2[ct][r2] + bv);
      }
    }
  }
}

// ---------------------------------------------------------------------------
// Fused final classifier (block = 64 target edges):
//   o1 = relu(tea@mw1c + b1 + P12f[ts,0:50] + P12f[td,50:100]);  (P12f bf16)
//   o2 = relu(o1@w2+b2); out = o2@w3+b3
// ---------------------------------------------------------------------------
__global__ __launch_bounds__(256) void final_fused2(
    const float* __restrict__ tea, const unsigned short* __restrict__ P12f,
    const int* __restrict__ eli, const unsigned short* __restrict__ B1t,
    const float* __restrict__ b1, const float* __restrict__ w2,
    const float* __restrict__ b2, const float* __restrict__ w3,
    const float* __restrict__ b3, float* __restrict__ out)
{
  __shared__ __align__(16) unsigned short As[64 * 104];
  __shared__ __align__(16) unsigned short Bs[64 * 104];
  __shared__ float o1s[64 * 51];
  __shared__ float o2s[64 * 25];
  __shared__ float w2s[50 * 25], w3s[50];
  __shared__ float b1s[64], b2s[25], b3s[2];
  __shared__ int sidx[64], didx[64];
  const int t = threadIdx.x;
  const int e0 = blockIdx.x * 64;
  for (int i = t; i < 832; i += 256) ((uint4*)Bs)[i] = ((const uint4*)B1t)[i];
  for (int i = t; i < 50 * 25; i += 256) w2s[i] = w2[i];
  if (t < 50) w3s[t] = w3[t];
  if (t < 64) { b1s[t] = (t < 50) ? b1[t] : 0.f; sidx[t] = eli[e0 + t]; didx[t] = eli[NT + e0 + t]; }
  if (t < 25) b2s[t] = b2[t];
  if (t < 2)  b3s[t] = b3[t];
  for (int i = t; i < 64 * 48; i += 256) {
    int r = i / 48, kk = (i - r * 48) * 2;
    unsigned short u0 = 0, u1 = 0;
    if (kk < 66) {
      float2 f = *(const float2*)(tea + (size_t)(e0 + r) * 66 + kk);
      u0 = f2b(f.x); u1 = f2b(f.y);
    }
    As[r * 104 + kk] = u0; As[r * 104 + kk + 1] = u1;
  }
  __syncthreads();
  const int lane = t & 63, w = t >> 6, m = lane & 15, q = lane >> 4;
  const unsigned short* Ap = As + (w * 16 + m) * 104 + q * 8;
  const unsigned short* Bp = Bs + m * 104 + q * 8;
  f32x4 acc[4] = {};
#pragma unroll
  for (int ks = 0; ks < 3; ks++) {
    short8 a = *(const short8*)(Ap + ks * 32);
#pragma unroll
    for (int ct = 0; ct < 4; ct++) {
      short8 b = *(const short8*)(Bp + ct * 16 * 104 + ks * 32);
      acc[ct] = __builtin_amdgcn_mfma_f32_16x16x32_bf16(a, b, acc[ct], 0, 0, 0);
    }
  }
#pragma unroll
  for (int ct = 0; ct < 4; ct++) {
    int c = ct * 16 + m;
    if (c < 50) {
      float bv = b1s[c];
#pragma unroll
      for (int r2 = 0; r2 < 4; r2++) {
        int e = w * 16 + q * 4 + r2;
        float v = acc[ct][r2] + bv + b2f(P12f[(size_t)sidx[e] * 100 + c])
                                   + b2f(P12f[(size_t)didx[e] * 100 + 50 + c]);
        o1s[e * 51 + c] = fmaxf(v, 0.f);
      }
    }
  }
  __syncthreads();
  for (int it = t; it < 64 * 25; it += 256) {
    int e = it / 25, c = it - e * 25;
    float s = b2s[c];
    for (int k = 0; k < 50; k++) s = fmaf(o1s[e * 51 + k], w2s[k * 25 + c], s);
    o2s[e * 25 + c] = fmaxf(s, 0.f);
  }
  __syncthreads();
  if (t < 128) {
    int e = t >> 1, c = t & 1;
    float s = b3s[c];
    for (int k = 0; k < 25; k++) s = fmaf(o2s[e * 25 + k], w3s[k * 2 + c], s);
    out[(size_t)(e0 + e) * 2 + c] = s;
  }
}

// ---------------------------------------------------------------------------
extern "C" void kernel_launch(void* const* d_in, const int* in_sizes, int n_in,
                              void* d_out, int out_size, void* d_ws, size_t ws_size,
                              hipStream_t stream) {
  const float* x      = (const float*)d_in[0];
  const int*   ei     = (const int*)  d_in[1];
  const float* eattr  = (const float*)d_in[2];
  const int*   eli    = (const int*)  d_in[3];
  const float* tattr  = (const float*)d_in[4];
  const float* node_w = (const float*)d_in[5];
  const float* node_b = (const float*)d_in[6];
  const float* edge_w = (const float*)d_in[7];
  const float* edge_b = (const float*)d_in[8];
  const float* cw1    = (const float*)d_in[9];
  const float* cb1    = (const float*)d_in[10];
  const float* cw2    = (const float*)d_in[11];
  const float* cb2    = (const float*)d_in[12];
  const float* bng    = (const float*)d_in[13];
  const float* bnb    = (const float*)d_in[14];
  const float* ew1    = (const float*)d_in[15];
  const float* eb1    = (const float*)d_in[16];
  const float* ew2    = (const float*)d_in[17];
  const float* eb2    = (const float*)d_in[18];
  const float* mw1    = (const float*)d_in[19];
  const float* mb1    = (const float*)d_in[20];
  const float* mw2    = (const float*)d_in[21];
  const float* mb2    = (const float*)d_in[22];
  const float* mw3    = (const float*)d_in[23];
  const float* mb3    = (const float*)d_in[24];
  float* out = (float*)d_out;

  // ---- workspace layout (optional eaW last) ----
  char* p = (char*)d_ws;
  auto alloc = [&](size_t bytes) { void* r = p; p += (bytes + 255) & ~(size_t)255; return r; };
  float* h      = (float*)alloc((size_t)NN * 66 * 4);
  unsigned short* hB = (unsigned short*)alloc((size_t)NN * 66 * 2);
  float* big    = (float*)alloc((size_t)NN * 132 * 4);  // P12(bf16) / midb
  float* zbuf   = (float*)alloc((size_t)NN * 66 * 4);   // aggr / z
  float* tea    = (float*)alloc((size_t)NT * 66 * 4);
  float* stat   = (float*)alloc(1024);
  int*   rowptr = (int*)alloc((NN + 1) * 4);
  int*   cur    = (int*)alloc((size_t)NN * 4);
  int*   bsum   = (int*)alloc((SCB + 1) * 4);
  int*   srcS   = (int*)alloc((size_t)NE * 4);
  int*   dstS   = (int*)alloc((size_t)NE * 4);
  int*   permS  = (int*)alloc((size_t)NE * 4);
  unsigned short* wT = (unsigned short*)alloc((size_t)140000 * 2);
  size_t used = (size_t)(p - (char*)d_ws);
  unsigned short* eaW = nullptr;
  if (ws_size >= used + (size_t)NE * 66 * 2 + 256)
    eaW = (unsigned short*)alloc((size_t)NE * 66 * 2);

  const int gN = (NN + 63) / 64;  // 1563
  const int gT = NT / 64;         // 3125
  const int gE = NE / 64;         // 15625

  // ---- CSR build ----
  hipMemsetAsync(cur, 0, (size_t)NN * sizeof(int), stream);
  hist_kernel<<<(NE + 255) / 256, 256, 0, stream>>>(ei, cur);
  blocksum_k<<<SCB, 256, 0, stream>>>(cur, bsum);
  scansums_k<<<1, 512, 0, stream>>>(bsum, rowptr);
  scatter_scan_k<<<SCB, 256, 0, stream>>>(cur, bsum, rowptr);
  hipMemsetAsync(cur, 0, (size_t)NN * sizeof(int), stream);
  fill_kernel<<<(NE + 255) / 256, 256, 0, stream>>>(ei, rowptr, cur, srcS, dstS, permS);

  // ---- weight prep ----
  PrepTab tb;
  int offs[14];
  int off = 0;
  auto set = [&](int s, const float* A, const float* B, int K, int C, int rows) {
    tb.a[s] = A; tb.b[s] = B; tb.K[s] = K; tb.C[s] = C; tb.rows[s] = rows;
    tb.off[s] = off; offs[s] = off; off += rows * 104;
  };
  set(0, node_w, nullptr, 64, 66, 80);
  set(1, edge_w, nullptr, 32, 66, 80);
  for (int l = 0; l < 2; l++) {
    set(2 + l, cw1 + (size_t)l * 4356, nullptr, 66, 66, 80);
    set(4 + l, cw2 + (size_t)l * 4356, nullptr, 66, 66, 80);
    set(6 + l, ew1 + (size_t)l * 13068 + 8712, nullptr, 66, 66, 80);       // W1c
    set(8 + l, ew2 + (size_t)l * 4356, nullptr, 66, 66, 80);
    set(10 + l, ew1 + (size_t)l * 13068, ew1 + (size_t)l * 13068 + 4356,   // W1a||W1b
        66, 66, 144);
  }
  set(12, mw1, mw1 + 3300, 66, 50, 112);   // A||B
  set(13, mw1 + 6600, nullptr, 66, 50, 80);  // C
  prep_w<<<14, 256, 0, stream>>>(tb, wT);

  // ---- one-time, layer-invariant ea projection (direct permS gather) ----
  if (eaW)
    eaw_kernel<<<gE, 256, 0, stream>>>(eattr, permS, wT + offs[1], edge_b, eaW);

  // ---- embeds ----
  mfma_gemm<64, 2, 5, 66, 0, 4><<<gN, 256, 0, stream>>>(
      x, nullptr, wT + offs[0], node_b, h, hB, NN);
  mfma_gemm<32, 1, 5, 66, 0, 0><<<gT, 256, 0, stream>>>(
      tattr, nullptr, wT + offs[1], edge_b, tea, nullptr, NT);

  for (int l = 0; l < 2; l++) {
    // aggregation
    hipMemsetAsync(zbuf, 0, (size_t)NN * 66 * sizeof(float), stream);
    if (eaW)
      msg_aggr4<<<gE, 256, 0, stream>>>(rowptr, srcS, dstS,
                                        (const unsigned int*)eaW,
                                        (const unsigned int*)hB, zbuf);
    else
      msg_aggr2<<<gE, 256, 0, stream>>>(rowptr, srcS, dstS, eattr, permS,
                                        wT + offs[1], edge_b, hB, zbuf);
    // node MLP: midb = bf16(relu((h+aggr)@cw1+b1)); z = midb@cw2+b2
    mfma_gemm<66, 3, 5, 66, 1, 3><<<gN, 256, 0, stream>>>(
        h, zbuf, wT + offs[2 + l], cb1 + l * 66, (unsigned short*)big, nullptr, NN);
    mfma_gemm<66, 3, 5, 66, 3, 0><<<gN, 256, 0, stream>>>(
        (unsigned short*)big, nullptr, wT + offs[4 + l], cb2 + l * 66, zbuf, nullptr, NN);
    // batchnorm + h update (refreshes hB mirror)
    hipMemsetAsync(stat, 0, 132 * sizeof(float), stream);
    bn_stats<<<(NN + 1023) / 1024, 256, 0, stream>>>(zbuf, stat);
    bn_update<<<(NN * 66 + 255) / 256, 256, 0, stream>>>(h, hB, zbuf, stat,
                                                         bng + l * 66, bnb + l * 66);
    // edge update: P12 = bf16(h @ [W1a||W1b]), then fused tile kernel
    mfma_gemm<66, 3, 9, 132, 0, 2><<<gN, 256, 0, stream>>>(
        h, nullptr, wT + offs[10 + l], nullptr, big, nullptr, NN);
    edge_fused2<<<gT, 256, 0, stream>>>((const unsigned short*)big, eli,
                                        wT + offs[6 + l], eb1 + l * 66,
                                        wT + offs[8 + l], eb2 + l * 66, tea);
  }

  // ---- final classifier ----
  mfma_gemm<66, 3, 7, 100, 2, 2><<<gN, 256, 0, stream>>>(
      h, nullptr, wT + offs[12], nullptr, big, nullptr, NN);
  final_fused2<<<gT, 256, 0, stream>>>(tea, (const unsigned short*)big, eli,
                                       wT + offs[13], mb1,
                                       mw2, mb2, mw3, mb3, out);
}

// Round 4
// 1309.287 us; speedup vs baseline: 1.4380x; 1.3770x over previous
//
#include <hip/hip_runtime.h>

#define NN 100000   // nodes
#define NE 1000000  // edges (divisible by 64)
#define NT 200000   // target edges (divisible by 64)
#define SCB 391     // ceil(NN/256) scan blocks

typedef __attribute__((ext_vector_type(8))) short short8;
typedef __attribute__((ext_vector_type(4))) float f32x4;

__device__ __forceinline__ unsigned short f2b(float x) {  // fp32 -> bf16 RNE
  union { float f; unsigned int u; } v; v.f = x;
  unsigned int r = v.u + 0x7fffu + ((v.u >> 16) & 1u);
  return (unsigned short)(r >> 16);
}
__device__ __forceinline__ float b2f(unsigned short x) {
  union { unsigned int u; float f; } v; v.u = ((unsigned int)x) << 16;
  return v.f;
}
__device__ __forceinline__ float uif(unsigned int u) {
  union { unsigned int u; float f; } v; v.u = u; return v.f;
}

// unpack 4 u32 (8 bf16) pairs, relu(a+h), store 8 f32 to LDS (two float4s)
__device__ __forceinline__ void relu8s(float* dst, uint4 a, uint4 h) {
  float4 lo, hi;
  lo.x = fmaxf(uif(a.x << 16) + uif(h.x << 16), 0.f);
  lo.y = fmaxf(uif(a.x & 0xffff0000u) + uif(h.x & 0xffff0000u), 0.f);
  lo.z = fmaxf(uif(a.y << 16) + uif(h.y << 16), 0.f);
  lo.w = fmaxf(uif(a.y & 0xffff0000u) + uif(h.y & 0xffff0000u), 0.f);
  hi.x = fmaxf(uif(a.z << 16) + uif(h.z << 16), 0.f);
  hi.y = fmaxf(uif(a.z & 0xffff0000u) + uif(h.z & 0xffff0000u), 0.f);
  hi.z = fmaxf(uif(a.w << 16) + uif(h.w << 16), 0.f);
  hi.w = fmaxf(uif(a.w & 0xffff0000u) + uif(h.w & 0xffff0000u), 0.f);
  *(float4*)dst = lo;
  *(float4*)(dst + 4) = hi;
}

// ---------------------------------------------------------------------------
// Weight prep: up to two fp32 sources [K][C] -> bf16 transposed tile
// [rows][104]; row c<C from A col c, C<=c<2C from B col c-C, rest zero.
// ---------------------------------------------------------------------------
struct PrepTab {
  const float* a[14]; const float* b[14];
  int K[14], C[14], rows[14], off[14];
};

__global__ __launch_bounds__(256) void prep_w(PrepTab tab, unsigned short* wT) {
  int s = blockIdx.x;
  const float* A = tab.a[s];
  const float* B = tab.b[s];
  int K = tab.K[s], C = tab.C[s], rows = tab.rows[s];
  unsigned short* dst = wT + tab.off[s];
  int n = rows * 104;
  for (int i = threadIdx.x; i < n; i += 256) {
    int c = i / 104, k = i - c * 104;
    float v = 0.0f;
    if (k < K) {
      if (c < C) v = A[k * C + c];
      else if (B && c < 2 * C) v = B[k * C + (c - C)];
    }
    dst[i] = f2b(v);
  }
}

// ---------------------------------------------------------------------------
// Generic MFMA row-GEMM: out[R,C] = act(in (+add)) @ W + bias
// AIN: 0=f32, 1=f32+add, 2=relu(f32), 3=bf16 input.
// ROUT bit0=relu, bit1=bf16 out, bit2=also write bf16 mirror to out2
// (mirror stride 72, zero-padded cols 66..71 for the padded hB layout).
// ---------------------------------------------------------------------------
template<int K, int KSTEPS, int CT, int C, int AIN, int ROUT>
__global__ __launch_bounds__(256) void mfma_gemm(
    const void* __restrict__ in, const float* __restrict__ add,
    const unsigned short* __restrict__ Bt, const float* __restrict__ bias,
    void* __restrict__ outp, void* __restrict__ out2, int R)
{
  constexpr int CR = CT * 16;
  __shared__ __align__(16) unsigned short As[64 * 104];
  __shared__ __align__(16) unsigned short Bs[CR * 104];
  __shared__ float bs[CR];
  const int t = threadIdx.x;
  const int r0 = blockIdx.x * 64;
  for (int i = t; i < CT * 208; i += 256) ((uint4*)Bs)[i] = ((const uint4*)Bt)[i];
  if (t < CR) bs[t] = (bias && t < C) ? bias[t] : 0.0f;
  constexpr int KH = KSTEPS * 16;  // float2 slots per row
  for (int i = t; i < 64 * KH; i += 256) {
    int r = i / KH, kk = (i - r * KH) * 2;
    int rg = r0 + r;
    unsigned short u0 = 0, u1 = 0;
    if (rg < R && kk < K) {
      if constexpr (AIN == 3) {
        unsigned int u = ((const unsigned int*)in)[((size_t)rg * K + kk) >> 1];
        u0 = u & 0xffffu; u1 = u >> 16;
      } else {
        float2 f = *(const float2*)((const float*)in + (size_t)rg * K + kk);
        float v0 = f.x, v1 = f.y;
        if constexpr (AIN == 1) {
          float2 g = *(const float2*)(add + (size_t)rg * K + kk);
          v0 += g.x; v1 += g.y;
        }
        if constexpr (AIN == 2) { v0 = fmaxf(v0, 0.f); v1 = fmaxf(v1, 0.f); }
        u0 = f2b(v0); u1 = f2b(v1);
      }
    }
    As[r * 104 + kk] = u0; As[r * 104 + kk + 1] = u1;
  }
  __syncthreads();
  const int lane = t & 63, w = t >> 6, m = lane & 15, q = lane >> 4;
  f32x4 acc[CT] = {};
  const unsigned short* Ap = As + (w * 16 + m) * 104 + q * 8;
  const unsigned short* Bp = Bs + m * 104 + q * 8;
#pragma unroll
  for (int ks = 0; ks < KSTEPS; ks++) {
    short8 a = *(const short8*)(Ap + ks * 32);
#pragma unroll
    for (int ct = 0; ct < CT; ct++) {
      short8 b = *(const short8*)(Bp + ct * 16 * 104 + ks * 32);
      acc[ct] = __builtin_amdgcn_mfma_f32_16x16x32_bf16(a, b, acc[ct], 0, 0, 0);
    }
  }
#pragma unroll
  for (int ct = 0; ct < CT; ct++) {
    int c = ct * 16 + m;
    float bv = bs[c];
#pragma unroll
    for (int r2 = 0; r2 < 4; r2++) {
      int row = r0 + w * 16 + q * 4 + r2;
      if (row < R) {
        if (c < C) {
          float v = acc[ct][r2] + bv;
          if constexpr ((ROUT & 1) != 0) v = fmaxf(v, 0.f);
          if constexpr ((ROUT & 2) != 0)
            ((unsigned short*)outp)[(size_t)row * C + c] = f2b(v);
          else
            ((float*)outp)[(size_t)row * C + c] = v;
          if constexpr ((ROUT & 4) != 0)
            ((unsigned short*)out2)[(size_t)row * 72 + c] = f2b(v);
        } else if constexpr ((ROUT & 4) != 0) {
          if (c < 72) ((unsigned short*)out2)[(size_t)row * 72 + c] = 0;
        }
      }
    }
  }
}

// ---------------------------------------------------------------------------
// CSR build: histogram + 3-pass coalesced scan + fill
// ---------------------------------------------------------------------------
__global__ __launch_bounds__(256) void hist_kernel(const int* __restrict__ ei,
                                                   int* __restrict__ deg)
{
  int e = blockIdx.x * 256 + threadIdx.x;
  if (e < NE) atomicAdd(&deg[ei[NE + e]], 1);
}

__global__ __launch_bounds__(256) void blocksum_k(const int* __restrict__ deg,
                                                  int* __restrict__ bsum)
{
  __shared__ int red[256];
  const int t = threadIdx.x;
  int i = blockIdx.x * 256 + t;
  red[t] = (i < NN) ? deg[i] : 0;
  __syncthreads();
  for (int s = 128; s > 0; s >>= 1) {
    if (t < s) red[t] += red[t + s];
    __syncthreads();
  }
  if (t == 0) bsum[blockIdx.x] = red[0];
}

__global__ __launch_bounds__(512) void scansums_k(int* __restrict__ bsum,
                                                  int* __restrict__ rowptr)
{
  __shared__ int s[512];
  const int t = threadIdx.x;
  s[t] = (t < SCB) ? bsum[t] : 0;
  __syncthreads();
  for (int off = 1; off < 512; off <<= 1) {
    int v = (t >= off) ? s[t - off] : 0;
    __syncthreads();
    s[t] += v;
    __syncthreads();
  }
  if (t < SCB) bsum[t] = (t == 0) ? 0 : s[t - 1];  // exclusive
  if (t == 0) rowptr[NN] = NE;
}

__global__ __launch_bounds__(256) void scatter_scan_k(
    const int* __restrict__ deg, const int* __restrict__ bsum,
    int* __restrict__ rowptr)
{
  __shared__ int s[256];
  const int t = threadIdx.x;
  int i = blockIdx.x * 256 + t;
  int v = (i < NN) ? deg[i] : 0;
  s[t] = v;
  __syncthreads();
  for (int off = 1; off < 256; off <<= 1) {
    int x = (t >= off) ? s[t - off] : 0;
    __syncthreads();
    s[t] += x;
    __syncthreads();
  }
  if (i < NN) rowptr[i] = bsum[blockIdx.x] + s[t] - v;
}

__global__ __launch_bounds__(256) void fill_kernel(
    const int* __restrict__ ei, const int* __restrict__ rowptr,
    int* __restrict__ cur, int* __restrict__ srcS, int* __restrict__ dstS,
    int* __restrict__ permS)
{
  int e = blockIdx.x * 256 + threadIdx.x;
  if (e >= NE) return;
  int d = ei[NE + e];
  int pos = atomicAdd(&cur[d], 1);
  int w = rowptr[d] + pos;
  srcS[w] = ei[e];
  dstS[w] = d;
  permS[w] = e;
}

// ---------------------------------------------------------------------------
// One-time, layer-invariant: eaW[w] = edge_attr[perm[w]] @ edge_w + edge_b
// (dst-sorted, bf16, stride 72 with zero pad). Gathers eattr via permS.
// ---------------------------------------------------------------------------
__global__ __launch_bounds__(256) void eaw_kernel(
    const float* __restrict__ eattr, const int* __restrict__ permS,
    const unsigned short* __restrict__ Bt, const float* __restrict__ bias,
    unsigned short* __restrict__ eaW)
{
  __shared__ __align__(16) unsigned short As[64 * 40];
  __shared__ __align__(16) unsigned short Bs[80 * 104];
  __shared__ float bs[80];
  const int t = threadIdx.x;
  const int e0 = blockIdx.x * 64;
  for (int i = t; i < 1040; i += 256) ((uint4*)Bs)[i] = ((const uint4*)Bt)[i];
  if (t < 80) bs[t] = (t < 66) ? bias[t] : 0.0f;
  for (int i = t; i < 1024; i += 256) {
    int r = i >> 4, j = i & 15;
    int p = permS[e0 + r];
    float2 f = ((const float2*)(eattr + (size_t)p * 32))[j];
    As[r * 40 + j * 2] = f2b(f.x);
    As[r * 40 + j * 2 + 1] = f2b(f.y);
  }
  __syncthreads();
  const int lane = t & 63, w = t >> 6, m = lane & 15, q = lane >> 4;
  f32x4 acc[5] = {};
  short8 a = *(const short8*)(As + (w * 16 + m) * 40 + q * 8);
#pragma unroll
  for (int ct = 0; ct < 5; ct++) {
    short8 b = *(const short8*)(Bs + (ct * 16 + m) * 104 + q * 8);
    acc[ct] = __builtin_amdgcn_mfma_f32_16x16x32_bf16(a, b, acc[ct], 0, 0, 0);
  }
#pragma unroll
  for (int ct = 0; ct < 5; ct++) {
    int c = ct * 16 + m;
    if (c < 66) {
      float bv = bs[c];
#pragma unroll
      for (int r2 = 0; r2 < 4; r2++) {
        int e = w * 16 + q * 4 + r2;
        eaW[(size_t)(e0 + e) * 72 + c] = f2b(acc[ct][r2] + bv);
      }
    } else if (c < 72) {
#pragma unroll
      for (int r2 = 0; r2 < 4; r2++) {
        int e = w * 16 + q * 4 + r2;
        eaW[(size_t)(e0 + e) * 72 + c] = 0;
      }
    }
  }
}

// ---------------------------------------------------------------------------
// Edge-centric aggregation v5: block = 64 dst-sorted edges. eaW/hB rows are
// padded to 144B (36 u32, 16B-aligned, zero pad) so phase A is 4 threads/edge
// x up-to-3 uint4 loads per stream, ALL issued before use (MLP ~6 vs ~1 in
// v3). relu(ea+h) -> msgS via float4 ds_writes. Phase B: per-(run,col-pair)
// float2 sums, 2-way unrolled. No LDS atomics anywhere (CAS-loop poison).
// ---------------------------------------------------------------------------
__global__ __launch_bounds__(256) void msg_aggr5(
    const int* __restrict__ rowptr, const int* __restrict__ srcS,
    const int* __restrict__ dstS, const unsigned int* __restrict__ eaW32,
    const unsigned int* __restrict__ hB32, float* __restrict__ aggr)
{
  __shared__ float msgS[64 * 76];
  __shared__ int sidx[64], didx[64];
  __shared__ int runStart[65];
  __shared__ int nrunsS;
  const int t = threadIdx.x;
  const int e0 = blockIdx.x * 64;
  if (t < 64) {
    int sv = srcS[e0 + t];
    int dv = dstS[e0 + t];
    sidx[t] = sv; didx[t] = dv;
    int dprev = __shfl_up(dv, 1);
    bool b = (t == 0) || (dv != dprev);
    unsigned long long mask = __ballot(b);
    int below = __popcll(mask & ((1ull << t) - 1ull));
    if (b) runStart[below] = t;
    if (t == 63) { nrunsS = __popcll(mask); runStart[__popcll(mask)] = 64; }
  }
  __syncthreads();
  // ---- phase A: 64 edges x 36 u32, 4 threads/edge, batched uint4 loads ----
  const int e = t >> 2, q = t & 3;
  const unsigned int* ea = eaW32 + (size_t)(e0 + e) * 36;
  const unsigned int* ph = hB32 + (size_t)sidx[e] * 36;
  uint4 a0 = *(const uint4*)(ea + q * 4);
  uint4 h0 = *(const uint4*)(ph + q * 4);
  uint4 a1 = *(const uint4*)(ea + q * 4 + 16);
  uint4 h1 = *(const uint4*)(ph + q * 4 + 16);
  uint4 a2 = {}, h2 = {};
  if (q == 0) { a2 = *(const uint4*)(ea + 32); h2 = *(const uint4*)(ph + 32); }
  float* mrow = msgS + e * 76;
  relu8s(mrow + q * 8, a0, h0);
  relu8s(mrow + q * 8 + 32, a1, h1);
  if (q == 0) relu8s(mrow + 64, a2, h2);
  __syncthreads();
  // ---- phase B: segmented sums, 33 col-pairs per run ----
  const int nr = nrunsS;
  for (int task = t; task < nr * 33; task += 256) {
    int r = task / 33, pp = task - r * 33;
    int c = pp * 2;
    int s0 = runStart[r], s1 = runStart[r + 1];
    float x0 = 0.f, x1 = 0.f, y0 = 0.f, y1 = 0.f;
    int ee = s0;
    for (; ee + 1 < s1; ee += 2) {
      float2 u = *(const float2*)(msgS + ee * 76 + c);
      float2 v = *(const float2*)(msgS + (ee + 1) * 76 + c);
      x0 += u.x; x1 += u.y; y0 += v.x; y1 += v.y;
    }
    if (ee < s1) {
      float2 u = *(const float2*)(msgS + ee * 76 + c);
      x0 += u.x; x1 += u.y;
    }
    x0 += y0; x1 += y1;
    int n = didx[s0];
    bool partial = false;
    if (r == 0)      partial = (rowptr[n] < e0);
    if (r == nr - 1) partial = partial || (rowptr[n + 1] > e0 + 64);
    if (partial) {
      atomicAdd(&aggr[(size_t)n * 66 + c], x0);
      atomicAdd(&aggr[(size_t)n * 66 + c + 1], x1);
    } else {
      float2 s; s.x = x0; s.y = x1;
      *(float2*)(&aggr[(size_t)n * 66 + c]) = s;
    }
  }
}

// ---------------------------------------------------------------------------
// Fallback (ws too small for eaW): fused MFMA message+aggregate, edge-centric.
// ---------------------------------------------------------------------------
__global__ __launch_bounds__(256) void msg_aggr2(
    const int* __restrict__ rowptr, const int* __restrict__ srcS,
    const int* __restrict__ dstS,
    const float* __restrict__ eattr, const int* __restrict__ permS,
    const unsigned short* __restrict__ Bt, const float* __restrict__ bias,
    const unsigned short* __restrict__ hB, float* __restrict__ aggr)
{
  __shared__ __align__(16) unsigned short As[64 * 40];
  __shared__ __align__(16) unsigned short Bs[80 * 104];
  __shared__ float msgS[64 * 67];
  __shared__ float bs[80];
  __shared__ int sidx[64], didx[64];
  __shared__ int runStart[65];
  __shared__ int nrunsS;
  const int t = threadIdx.x;
  const int e0 = blockIdx.x * 64;
  for (int i = t; i < 1040; i += 256) ((uint4*)Bs)[i] = ((const uint4*)Bt)[i];
  if (t < 80) bs[t] = (t < 66) ? bias[t] : 0.0f;
  if (t < 64) { sidx[t] = srcS[e0 + t]; didx[t] = dstS[e0 + t]; }
  for (int i = t; i < 1024; i += 256) {
    int r = i >> 4, j = i & 15;
    int p = permS[e0 + r];
    float2 f = ((const float2*)(eattr + (size_t)p * 32))[j];
    As[r * 40 + j * 2] = f2b(f.x);
    As[r * 40 + j * 2 + 1] = f2b(f.y);
  }
  __syncthreads();
  if (t < 64) {
    int dv = didx[t];
    int dprev = __shfl_up(dv, 1);
    bool b = (t == 0) || (dv != dprev);
    unsigned long long mask = __ballot(b);
    int idx = __popcll(mask & ((1ull << t) - 1ull));
    if (b) runStart[idx] = t;
    if (t == 63) { nrunsS = __popcll(mask); runStart[__popcll(mask)] = 64; }
  }
  const int lane = t & 63, w = t >> 6, m = lane & 15, q = lane >> 4;
  f32x4 acc[5] = {};
  short8 a = *(const short8*)(As + (w * 16 + m) * 40 + q * 8);
#pragma unroll
  for (int ct = 0; ct < 5; ct++) {
    short8 b = *(const short8*)(Bs + (ct * 16 + m) * 104 + q * 8);
    acc[ct] = __builtin_amdgcn_mfma_f32_16x16x32_bf16(a, b, acc[ct], 0, 0, 0);
  }
#pragma unroll
  for (int ct = 0; ct < 5; ct++) {
    int c = ct * 16 + m;
    if (c < 66) {
      float bv = bs[c];
#pragma unroll
      for (int r2 = 0; r2 < 4; r2++) {
        int e = w * 16 + q * 4 + r2;
        float v = acc[ct][r2] + bv + b2f(hB[(size_t)sidx[e] * 72 + c]);
        msgS[e * 67 + c] = fmaxf(v, 0.f);
      }
    }
  }
  __syncthreads();
  const int nr = nrunsS;
  for (int task = t; task < nr * 66; task += 256) {
    int r = task / 66, c = task - r * 66;
    int s0 = runStart[r], s1 = runStart[r + 1];
    float s = 0.0f;
    for (int e = s0; e < s1; e++) s += msgS[e * 67 + c];
    int n = didx[s0];
    bool partial = false;
    if (r == 0)      partial = (rowptr[n] < e0);
    if (r == nr - 1) partial = partial || (rowptr[n + 1] > e0 + 64);
    if (partial) atomicAdd(&aggr[(size_t)n * 66 + c], s);
    else         aggr[(size_t)n * 66 + c] = s;
  }
}

// ---------------------------------------------------------------------------
// BatchNorm stats + update (fp32); bn_update also refreshes hB mirror.
// ---------------------------------------------------------------------------
__global__ __launch_bounds__(256) void bn_stats(const float* __restrict__ z,
                                                float* __restrict__ stat)
{
  const int t = threadIdx.x;
  if (t >= 198) return;
  const int c = t % 66, rs = t / 66;
  const int r0 = blockIdx.x * 1024;
  float s1 = 0.0f, s2 = 0.0f;
  int rend = r0 + 1024; if (rend > NN) rend = NN;
  for (int r = r0 + rs; r < rend; r += 3) {
    float v = z[(size_t)r * 66 + c];
    s1 += v; s2 += v * v;
  }
  atomicAdd(&stat[c], s1);
  atomicAdd(&stat[66 + c], s2);
}

__global__ __launch_bounds__(256) void bn_update(
    float* __restrict__ h, unsigned short* __restrict__ hB,
    const float* __restrict__ z, const float* __restrict__ stat,
    const float* __restrict__ gamma, const float* __restrict__ beta)
{
  int idx = blockIdx.x * 256 + threadIdx.x;
  if (idx >= NN * 66) return;
  int c = idx % 66;
  int r = idx / 66;
  float mean = stat[c] * (1.0f / NN);
  float var  = stat[66 + c] * (1.0f / NN) - mean * mean;
  float inv  = rsqrtf(var + 1e-5f);
  float zn   = (z[idx] - mean) * inv * gamma[c] + beta[c];
  float v = 0.5f * (h[idx] + fmaxf(zn, 0.0f));
  h[idx] = v;
  hB[(size_t)r * 72 + c] = f2b(v);
}

// ---------------------------------------------------------------------------
// Fused edge update (block = 64 target edges), MFMA chain:
//   mid = relu(tea@W1c + b1 + P12[ts,0:66] + P12[td,66:132]);   (P12 bf16)
//   tea += 0.5*(mid@W2 + b2)
// ---------------------------------------------------------------------------
__global__ __launch_bounds__(256) void edge_fused2(
    const unsigned short* __restrict__ P12, const int* __restrict__ eli,
    const unsigned short* __restrict__ B1t, const float* __restrict__ b1,
    const unsigned short* __restrict__ B2t, const float* __restrict__ b2,
    float* __restrict__ tea)
{
  __shared__ __align__(16) unsigned short As[64 * 104];  // tea tile, then mid
  __shared__ __align__(16) unsigned short Bs1[80 * 104];
  __shared__ __align__(16) unsigned short Bs2[80 * 104];
  __shared__ float b1s[80], b2s[80];
  __shared__ int sidx[64], didx[64];
  const int t = threadIdx.x;
  const int e0 = blockIdx.x * 64;
  for (int i = t; i < 1040; i += 256) {
    ((uint4*)Bs1)[i] = ((const uint4*)B1t)[i];
    ((uint4*)Bs2)[i] = ((const uint4*)B2t)[i];
  }
  if (t < 80) { b1s[t] = (t < 66) ? b1[t] : 0.f; b2s[t] = (t < 66) ? b2[t] : 0.f; }
  if (t < 64) { sidx[t] = eli[e0 + t]; didx[t] = eli[NT + e0 + t]; }
  for (int i = t; i < 64 * 48; i += 256) {
    int r = i / 48, kk = (i - r * 48) * 2;
    unsigned short u0 = 0, u1 = 0;
    if (kk < 66) {
      float2 f = *(const float2*)(tea + (size_t)(e0 + r) * 66 + kk);
      u0 = f2b(f.x); u1 = f2b(f.y);
    }
    As[r * 104 + kk] = u0; As[r * 104 + kk + 1] = u1;
  }
  __syncthreads();
  const int lane = t & 63, w = t >> 6, m = lane & 15, q = lane >> 4;
  const unsigned short* Ap = As + (w * 16 + m) * 104 + q * 8;
  const unsigned short* Bp1 = Bs1 + m * 104 + q * 8;
  f32x4 acc[5] = {};
#pragma unroll
  for (int ks = 0; ks < 3; ks++) {
    short8 a = *(const short8*)(Ap + ks * 32);
#pragma unroll
    for (int ct = 0; ct < 5; ct++) {
      short8 b = *(const short8*)(Bp1 + ct * 16 * 104 + ks * 32);
      acc[ct] = __builtin_amdgcn_mfma_f32_16x16x32_bf16(a, b, acc[ct], 0, 0, 0);
    }
  }
  __syncthreads();  // GEMM1 reads of As done before mid overwrite
#pragma unroll
  for (int ct = 0; ct < 5; ct++) {
    int c = ct * 16 + m;
    if (c < 66) {
      float bv = b1s[c];
#pragma unroll
      for (int r2 = 0; r2 < 4; r2++) {
        int e = w * 16 + q * 4 + r2;
        float v = acc[ct][r2] + bv + b2f(P12[(size_t)sidx[e] * 132 + c])
                                   + b2f(P12[(size_t)didx[e] * 132 + 66 + c]);
        As[e * 104 + c] = f2b(fmaxf(v, 0.f));
      }
    }
  }
  __syncthreads();
  const unsigned short* Bp2 = Bs2 + m * 104 + q * 8;
  f32x4 acc2[5] = {};
#pragma unroll
  for (int ks = 0; ks < 3; ks++) {
    short8 a = *(const short8*)(Ap + ks * 32);
#pragma unroll
    for (int ct = 0; ct < 5; ct++) {
      short8 b = *(const short8*)(Bp2 + ct * 16 * 104 + ks * 32);
      acc2[ct] = __builtin_amdgcn_mfma_f32_16x16x32_bf16(a, b, acc2[ct], 0, 0, 0);
    }
  }
#pragma unroll
  for (int ct = 0; ct < 5; ct++) {
    int c = ct * 16 + m;
    if (c < 66) {
      float bv = b2s[c];
#pragma unroll
      for (int r2 = 0; r2 < 4; r2++) {
        int e = w * 16 + q * 4 + r2;
        size_t idx = (size_t)(e0 + e) * 66 + c;
        tea[idx] += 0.5f * (acc2[ct][r2] + bv);
      }
    }
  }
}

// ---------------------------------------------------------------------------
// Fused final classifier (block = 64 target edges):
//   o1 = relu(tea@mw1c + b1 + P12f[ts,0:50] + P12f[td,50:100]);  (P12f bf16)
//   o2 = relu(o1@w2+b2); out = o2@w3+b3
// ---------------------------------------------------------------------------
__global__ __launch_bounds__(256) void final_fused2(
    const float* __restrict__ tea, const unsigned short* __restrict__ P12f,
    const int* __restrict__ eli, const unsigned short* __restrict__ B1t,
    const float* __restrict__ b1, const float* __restrict__ w2,
    const float* __restrict__ b2, const float* __restrict__ w3,
    const float* __restrict__ b3, float* __restrict__ out)
{
  __shared__ __align__(16) unsigned short As[64 * 104];
  __shared__ __align__(16) unsigned short Bs[64 * 104];
  __shared__ float o1s[64 * 51];
  __shared__ float o2s[64 * 25];
  __shared__ float w2s[50 * 25], w3s[50];
  __shared__ float b1s[64], b2s[25], b3s[2];
  __shared__ int sidx[64], didx[64];
  const int t = threadIdx.x;
  const int e0 = blockIdx.x * 64;
  for (int i = t; i < 832; i += 256) ((uint4*)Bs)[i] = ((const uint4*)B1t)[i];
  for (int i = t; i < 50 * 25; i += 256) w2s[i] = w2[i];
  if (t < 50) w3s[t] = w3[t];
  if (t < 64) { b1s[t] = (t < 50) ? b1[t] : 0.f; sidx[t] = eli[e0 + t]; didx[t] = eli[NT + e0 + t]; }
  if (t < 25) b2s[t] = b2[t];
  if (t < 2)  b3s[t] = b3[t];
  for (int i = t; i < 64 * 48; i += 256) {
    int r = i / 48, kk = (i - r * 48) * 2;
    unsigned short u0 = 0, u1 = 0;
    if (kk < 66) {
      float2 f = *(const float2*)(tea + (size_t)(e0 + r) * 66 + kk);
      u0 = f2b(f.x); u1 = f2b(f.y);
    }
    As[r * 104 + kk] = u0; As[r * 104 + kk + 1] = u1;
  }
  __syncthreads();
  const int lane = t & 63, w = t >> 6, m = lane & 15, q = lane >> 4;
  const unsigned short* Ap = As + (w * 16 + m) * 104 + q * 8;
  const unsigned short* Bp = Bs + m * 104 + q * 8;
  f32x4 acc[4] = {};
#pragma unroll
  for (int ks = 0; ks < 3; ks++) {
    short8 a = *(const short8*)(Ap + ks * 32);
#pragma unroll
    for (int ct = 0; ct < 4; ct++) {
      short8 b = *(const short8*)(Bp + ct * 16 * 104 + ks * 32);
      acc[ct] = __builtin_amdgcn_mfma_f32_16x16x32_bf16(a, b, acc[ct], 0, 0, 0);
    }
  }
#pragma unroll
  for (int ct = 0; ct < 4; ct++) {
    int c = ct * 16 + m;
    if (c < 50) {
      float bv = b1s[c];
#pragma unroll
      for (int r2 = 0; r2 < 4; r2++) {
        int e = w * 16 + q * 4 + r2;
        float v = acc[ct][r2] + bv + b2f(P12f[(size_t)sidx[e] * 100 + c])
                                   + b2f(P12f[(size_t)didx[e] * 100 + 50 + c]);
        o1s[e * 51 + c] = fmaxf(v, 0.f);
      }
    }
  }
  __syncthreads();
  for (int it = t; it < 64 * 25; it += 256) {
    int e = it / 25, c = it - e * 25;
    float s = b2s[c];
    for (int k = 0; k < 50; k++) s = fmaf(o1s[e * 51 + k], w2s[k * 25 + c], s);
    o2s[e * 25 + c] = fmaxf(s, 0.f);
  }
  __syncthreads();
  if (t < 128) {
    int e = t >> 1, c = t & 1;
    float s = b3s[c];
    for (int k = 0; k < 25; k++) s = fmaf(o2s[e * 25 + k], w3s[k * 2 + c], s);
    out[(size_t)(e0 + e) * 2 + c] = s;
  }
}

// ---------------------------------------------------------------------------
extern "C" void kernel_launch(void* const* d_in, const int* in_sizes, int n_in,
                              void* d_out, int out_size, void* d_ws, size_t ws_size,
                              hipStream_t stream) {
  const float* x      = (const float*)d_in[0];
  const int*   ei     = (const int*)  d_in[1];
  const float* eattr  = (const float*)d_in[2];
  const int*   eli    = (const int*)  d_in[3];
  const float* tattr  = (const float*)d_in[4];
  const float* node_w = (const float*)d_in[5];
  const float* node_b = (const float*)d_in[6];
  const float* edge_w = (const float*)d_in[7];
  const float* edge_b = (const float*)d_in[8];
  const float* cw1    = (const float*)d_in[9];
  const float* cb1    = (const float*)d_in[10];
  const float* cw2    = (const float*)d_in[11];
  const float* cb2    = (const float*)d_in[12];
  const float* bng    = (const float*)d_in[13];
  const float* bnb    = (const float*)d_in[14];
  const float* ew1    = (const float*)d_in[15];
  const float* eb1    = (const float*)d_in[16];
  const float* ew2    = (const float*)d_in[17];
  const float* eb2    = (const float*)d_in[18];
  const float* mw1    = (const float*)d_in[19];
  const float* mb1    = (const float*)d_in[20];
  const float* mw2    = (const float*)d_in[21];
  const float* mb2    = (const float*)d_in[22];
  const float* mw3    = (const float*)d_in[23];
  const float* mb3    = (const float*)d_in[24];
  float* out = (float*)d_out;

  // ---- workspace layout (optional eaW last) ----
  char* p = (char*)d_ws;
  auto alloc = [&](size_t bytes) { void* r = p; p += (bytes + 255) & ~(size_t)255; return r; };
  float* h      = (float*)alloc((size_t)NN * 66 * 4);
  unsigned short* hB = (unsigned short*)alloc((size_t)NN * 72 * 2);  // padded 144B rows
  float* big    = (float*)alloc((size_t)NN * 132 * 4);  // P12(bf16) / midb
  float* zbuf   = (float*)alloc((size_t)NN * 66 * 4);   // aggr / z
  float* tea    = (float*)alloc((size_t)NT * 66 * 4);
  float* stat   = (float*)alloc(1024);
  int*   rowptr = (int*)alloc((NN + 1) * 4);
  int*   cur    = (int*)alloc((size_t)NN * 4);
  int*   bsum   = (int*)alloc((SCB + 1) * 4);
  int*   srcS   = (int*)alloc((size_t)NE * 4);
  int*   dstS   = (int*)alloc((size_t)NE * 4);
  int*   permS  = (int*)alloc((size_t)NE * 4);
  unsigned short* wT = (unsigned short*)alloc((size_t)140000 * 2);
  size_t used = (size_t)(p - (char*)d_ws);
  unsigned short* eaW = nullptr;
  if (ws_size >= used + (size_t)NE * 72 * 2 + 256)
    eaW = (unsigned short*)alloc((size_t)NE * 72 * 2);  // padded 144B rows

  const int gN = (NN + 63) / 64;  // 1563
  const int gT = NT / 64;         // 3125
  const int gE = NE / 64;         // 15625

  // ---- CSR build ----
  hipMemsetAsync(cur, 0, (size_t)NN * sizeof(int), stream);
  hist_kernel<<<(NE + 255) / 256, 256, 0, stream>>>(ei, cur);
  blocksum_k<<<SCB, 256, 0, stream>>>(cur, bsum);
  scansums_k<<<1, 512, 0, stream>>>(bsum, rowptr);
  scatter_scan_k<<<SCB, 256, 0, stream>>>(cur, bsum, rowptr);
  hipMemsetAsync(cur, 0, (size_t)NN * sizeof(int), stream);
  fill_kernel<<<(NE + 255) / 256, 256, 0, stream>>>(ei, rowptr, cur, srcS, dstS, permS);

  // ---- weight prep ----
  PrepTab tb;
  int offs[14];
  int off = 0;
  auto set = [&](int s, const float* A, const float* B, int K, int C, int rows) {
    tb.a[s] = A; tb.b[s] = B; tb.K[s] = K; tb.C[s] = C; tb.rows[s] = rows;
    tb.off[s] = off; offs[s] = off; off += rows * 104;
  };
  set(0, node_w, nullptr, 64, 66, 80);
  set(1, edge_w, nullptr, 32, 66, 80);
  for (int l = 0; l < 2; l++) {
    set(2 + l, cw1 + (size_t)l * 4356, nullptr, 66, 66, 80);
    set(4 + l, cw2 + (size_t)l * 4356, nullptr, 66, 66, 80);
    set(6 + l, ew1 + (size_t)l * 13068 + 8712, nullptr, 66, 66, 80);       // W1c
    set(8 + l, ew2 + (size_t)l * 4356, nullptr, 66, 66, 80);
    set(10 + l, ew1 + (size_t)l * 13068, ew1 + (size_t)l * 13068 + 4356,   // W1a||W1b
        66, 66, 144);
  }
  set(12, mw1, mw1 + 3300, 66, 50, 112);   // A||B
  set(13, mw1 + 6600, nullptr, 66, 50, 80);  // C
  prep_w<<<14, 256, 0, stream>>>(tb, wT);

  // ---- one-time, layer-invariant ea projection (direct permS gather) ----
  if (eaW)
    eaw_kernel<<<gE, 256, 0, stream>>>(eattr, permS, wT + offs[1], edge_b, eaW);

  // ---- embeds ----
  mfma_gemm<64, 2, 5, 66, 0, 4><<<gN, 256, 0, stream>>>(
      x, nullptr, wT + offs[0], node_b, h, hB, NN);
  mfma_gemm<32, 1, 5, 66, 0, 0><<<gT, 256, 0, stream>>>(
      tattr, nullptr, wT + offs[1], edge_b, tea, nullptr, NT);

  for (int l = 0; l < 2; l++) {
    // aggregation
    hipMemsetAsync(zbuf, 0, (size_t)NN * 66 * sizeof(float), stream);
    if (eaW)
      msg_aggr5<<<gE, 256, 0, stream>>>(rowptr, srcS, dstS,
                                        (const unsigned int*)eaW,
                                        (const unsigned int*)hB, zbuf);
    else
      msg_aggr2<<<gE, 256, 0, stream>>>(rowptr, srcS, dstS, eattr, permS,
                                        wT + offs[1], edge_b, hB, zbuf);
    // node MLP: midb = bf16(relu((h+aggr)@cw1+b1)); z = midb@cw2+b2
    mfma_gemm<66, 3, 5, 66, 1, 3><<<gN, 256, 0, stream>>>(
        h, zbuf, wT + offs[2 + l], cb1 + l * 66, (unsigned short*)big, nullptr, NN);
    mfma_gemm<66, 3, 5, 66, 3, 0><<<gN, 256, 0, stream>>>(
        (unsigned short*)big, nullptr, wT + offs[4 + l], cb2 + l * 66, zbuf, nullptr, NN);
    // batchnorm + h update (refreshes hB mirror)
    hipMemsetAsync(stat, 0, 132 * sizeof(float), stream);
    bn_stats<<<(NN + 1023) / 1024, 256, 0, stream>>>(zbuf, stat);
    bn_update<<<(NN * 66 + 255) / 256, 256, 0, stream>>>(h, hB, zbuf, stat,
                                                         bng + l * 66, bnb + l * 66);
    // edge update: P12 = bf16(h @ [W1a||W1b]), then fused tile kernel
    mfma_gemm<66, 3, 9, 132, 0, 2><<<gN, 256, 0, stream>>>(
        h, nullptr, wT + offs[10 + l], nullptr, big, nullptr, NN);
    edge_fused2<<<gT, 256, 0, stream>>>((const unsigned short*)big, eli,
                                        wT + offs[6 + l], eb1 + l * 66,
                                        wT + offs[8 + l], eb2 + l * 66, tea);
  }

  // ---- final classifier ----
  mfma_gemm<66, 3, 7, 100, 2, 2><<<gN, 256, 0, stream>>>(
      h, nullptr, wT + offs[12], nullptr, big, nullptr, NN);
  final_fused2<<<gT, 256, 0, stream>>>(tea, (const unsigned short*)big, eli,
                                       wT + offs[13], mb1,
                                       mw2, mb2, mw3, mb3, out);
}

// Round 5
// 1280.009 us; speedup vs baseline: 1.4709x; 1.0229x over previous
//
#include <hip/hip_runtime.h>

#define NN 100000   // nodes
#define NE 1000000  // edges (divisible by 64)
#define NT 200000   // target edges (divisible by 64)
#define SCB 391     // ceil(NN/256) scan blocks
#define EAW_TPB 8   // edge tiles per block in eaw_kernel

typedef __attribute__((ext_vector_type(8))) short short8;
typedef __attribute__((ext_vector_type(4))) float f32x4;

__device__ __forceinline__ unsigned short f2b(float x) {  // fp32 -> bf16 RNE
  union { float f; unsigned int u; } v; v.f = x;
  unsigned int r = v.u + 0x7fffu + ((v.u >> 16) & 1u);
  return (unsigned short)(r >> 16);
}
__device__ __forceinline__ float b2f(unsigned short x) {
  union { unsigned int u; float f; } v; v.u = ((unsigned int)x) << 16;
  return v.f;
}
__device__ __forceinline__ float uif(unsigned int u) {
  union { unsigned int u; float f; } v; v.u = u; return v.f;
}

// unpack 4 u32 (8 bf16) pairs, relu(a+h), store 8 f32 to LDS (two float4s)
__device__ __forceinline__ void relu8s(float* dst, uint4 a, uint4 h) {
  float4 lo, hi;
  lo.x = fmaxf(uif(a.x << 16) + uif(h.x << 16), 0.f);
  lo.y = fmaxf(uif(a.x & 0xffff0000u) + uif(h.x & 0xffff0000u), 0.f);
  lo.z = fmaxf(uif(a.y << 16) + uif(h.y << 16), 0.f);
  lo.w = fmaxf(uif(a.y & 0xffff0000u) + uif(h.y & 0xffff0000u), 0.f);
  hi.x = fmaxf(uif(a.z << 16) + uif(h.z << 16), 0.f);
  hi.y = fmaxf(uif(a.z & 0xffff0000u) + uif(h.z & 0xffff0000u), 0.f);
  hi.z = fmaxf(uif(a.w << 16) + uif(h.w << 16), 0.f);
  hi.w = fmaxf(uif(a.w & 0xffff0000u) + uif(h.w & 0xffff0000u), 0.f);
  *(float4*)dst = lo;
  *(float4*)(dst + 4) = hi;
}

// ---------------------------------------------------------------------------
// Weight prep: up to two fp32 sources [K][C] -> bf16 transposed tile
// [rows][104]; row c<C from A col c, C<=c<2C from B col c-C, rest zero.
// ---------------------------------------------------------------------------
struct PrepTab {
  const float* a[14]; const float* b[14];
  int K[14], C[14], rows[14], off[14];
};

__global__ __launch_bounds__(256) void prep_w(PrepTab tab, unsigned short* wT) {
  int s = blockIdx.x;
  const float* A = tab.a[s];
  const float* B = tab.b[s];
  int K = tab.K[s], C = tab.C[s], rows = tab.rows[s];
  unsigned short* dst = wT + tab.off[s];
  int n = rows * 104;
  for (int i = threadIdx.x; i < n; i += 256) {
    int c = i / 104, k = i - c * 104;
    float v = 0.0f;
    if (k < K) {
      if (c < C) v = A[k * C + c];
      else if (B && c < 2 * C) v = B[k * C + (c - C)];
    }
    dst[i] = f2b(v);
  }
}

// ---------------------------------------------------------------------------
// Generic MFMA row-GEMM: out[R,C] = act(in (+add)) @ W + bias
// AIN: 0=f32, 1=f32+add, 2=relu(f32), 3=bf16 input.
// ROUT bit0=relu, bit1=bf16 out, bit2=also write bf16 mirror to out2
// (mirror stride 72, zero-padded cols 66..71 for the padded hB layout).
// ---------------------------------------------------------------------------
template<int K, int KSTEPS, int CT, int C, int AIN, int ROUT>
__global__ __launch_bounds__(256) void mfma_gemm(
    const void* __restrict__ in, const float* __restrict__ add,
    const unsigned short* __restrict__ Bt, const float* __restrict__ bias,
    void* __restrict__ outp, void* __restrict__ out2, int R)
{
  constexpr int CR = CT * 16;
  __shared__ __align__(16) unsigned short As[64 * 104];
  __shared__ __align__(16) unsigned short Bs[CR * 104];
  __shared__ float bs[CR];
  const int t = threadIdx.x;
  const int r0 = blockIdx.x * 64;
  for (int i = t; i < CT * 208; i += 256) ((uint4*)Bs)[i] = ((const uint4*)Bt)[i];
  if (t < CR) bs[t] = (bias && t < C) ? bias[t] : 0.0f;
  constexpr int KH = KSTEPS * 16;  // float2 slots per row
  for (int i = t; i < 64 * KH; i += 256) {
    int r = i / KH, kk = (i - r * KH) * 2;
    int rg = r0 + r;
    unsigned short u0 = 0, u1 = 0;
    if (rg < R && kk < K) {
      if constexpr (AIN == 3) {
        unsigned int u = ((const unsigned int*)in)[((size_t)rg * K + kk) >> 1];
        u0 = u & 0xffffu; u1 = u >> 16;
      } else {
        float2 f = *(const float2*)((const float*)in + (size_t)rg * K + kk);
        float v0 = f.x, v1 = f.y;
        if constexpr (AIN == 1) {
          float2 g = *(const float2*)(add + (size_t)rg * K + kk);
          v0 += g.x; v1 += g.y;
        }
        if constexpr (AIN == 2) { v0 = fmaxf(v0, 0.f); v1 = fmaxf(v1, 0.f); }
        u0 = f2b(v0); u1 = f2b(v1);
      }
    }
    As[r * 104 + kk] = u0; As[r * 104 + kk + 1] = u1;
  }
  __syncthreads();
  const int lane = t & 63, w = t >> 6, m = lane & 15, q = lane >> 4;
  f32x4 acc[CT] = {};
  const unsigned short* Ap = As + (w * 16 + m) * 104 + q * 8;
  const unsigned short* Bp = Bs + m * 104 + q * 8;
#pragma unroll
  for (int ks = 0; ks < KSTEPS; ks++) {
    short8 a = *(const short8*)(Ap + ks * 32);
#pragma unroll
    for (int ct = 0; ct < CT; ct++) {
      short8 b = *(const short8*)(Bp + ct * 16 * 104 + ks * 32);
      acc[ct] = __builtin_amdgcn_mfma_f32_16x16x32_bf16(a, b, acc[ct], 0, 0, 0);
    }
  }
#pragma unroll
  for (int ct = 0; ct < CT; ct++) {
    int c = ct * 16 + m;
    float bv = bs[c];
#pragma unroll
    for (int r2 = 0; r2 < 4; r2++) {
      int row = r0 + w * 16 + q * 4 + r2;
      if (row < R) {
        if (c < C) {
          float v = acc[ct][r2] + bv;
          if constexpr ((ROUT & 1) != 0) v = fmaxf(v, 0.f);
          if constexpr ((ROUT & 2) != 0)
            ((unsigned short*)outp)[(size_t)row * C + c] = f2b(v);
          else
            ((float*)outp)[(size_t)row * C + c] = v;
          if constexpr ((ROUT & 4) != 0)
            ((unsigned short*)out2)[(size_t)row * 72 + c] = f2b(v);
        } else if constexpr ((ROUT & 4) != 0) {
          if (c < 72) ((unsigned short*)out2)[(size_t)row * 72 + c] = 0;
        }
      }
    }
  }
}

// ---------------------------------------------------------------------------
// CSR build: histogram + 3-pass coalesced scan + fill
// ---------------------------------------------------------------------------
__global__ __launch_bounds__(256) void hist_kernel(const int* __restrict__ ei,
                                                   int* __restrict__ deg)
{
  int e = blockIdx.x * 256 + threadIdx.x;
  if (e < NE) atomicAdd(&deg[ei[NE + e]], 1);
}

__global__ __launch_bounds__(256) void blocksum_k(const int* __restrict__ deg,
                                                  int* __restrict__ bsum)
{
  __shared__ int red[256];
  const int t = threadIdx.x;
  int i = blockIdx.x * 256 + t;
  red[t] = (i < NN) ? deg[i] : 0;
  __syncthreads();
  for (int s = 128; s > 0; s >>= 1) {
    if (t < s) red[t] += red[t + s];
    __syncthreads();
  }
  if (t == 0) bsum[blockIdx.x] = red[0];
}

__global__ __launch_bounds__(512) void scansums_k(int* __restrict__ bsum,
                                                  int* __restrict__ rowptr)
{
  __shared__ int s[512];
  const int t = threadIdx.x;
  s[t] = (t < SCB) ? bsum[t] : 0;
  __syncthreads();
  for (int off = 1; off < 512; off <<= 1) {
    int v = (t >= off) ? s[t - off] : 0;
    __syncthreads();
    s[t] += v;
    __syncthreads();
  }
  if (t < SCB) bsum[t] = (t == 0) ? 0 : s[t - 1];  // exclusive
  if (t == 0) rowptr[NN] = NE;
}

__global__ __launch_bounds__(256) void scatter_scan_k(
    const int* __restrict__ deg, const int* __restrict__ bsum,
    int* __restrict__ rowptr)
{
  __shared__ int s[256];
  const int t = threadIdx.x;
  int i = blockIdx.x * 256 + t;
  int v = (i < NN) ? deg[i] : 0;
  s[t] = v;
  __syncthreads();
  for (int off = 1; off < 256; off <<= 1) {
    int x = (t >= off) ? s[t - off] : 0;
    __syncthreads();
    s[t] += x;
    __syncthreads();
  }
  if (i < NN) rowptr[i] = bsum[blockIdx.x] + s[t] - v;
}

__global__ __launch_bounds__(256) void fill_kernel(
    const int* __restrict__ ei, const int* __restrict__ rowptr,
    int* __restrict__ cur, int* __restrict__ srcS, int* __restrict__ dstS,
    int* __restrict__ permS)
{
  int e = blockIdx.x * 256 + threadIdx.x;
  if (e >= NE) return;
  int d = ei[NE + e];
  int pos = atomicAdd(&cur[d], 1);
  int w = rowptr[d] + pos;
  srcS[w] = ei[e];
  dstS[w] = d;
  permS[w] = e;
}

// ---------------------------------------------------------------------------
// One-time, layer-invariant: eaW[w] = edge_attr[perm[w]] @ edge_w + edge_b
// (dst-sorted, bf16, stride 72 with zero pad). v2: no LDS, no syncs.
// B-fragments + bias register-resident (Bt is L2-hot, shared by all blocks);
// each lane gathers its own A-fragment (two float4 = its 32B of the eattr
// row) directly from global. EAW_TPB tiles per block, unrolled for MLP.
// ---------------------------------------------------------------------------
__global__ __launch_bounds__(256) void eaw_kernel(
    const float* __restrict__ eattr, const int* __restrict__ permS,
    const unsigned short* __restrict__ Bt, const float* __restrict__ bias,
    unsigned short* __restrict__ eaW)
{
  const int t = threadIdx.x;
  const int lane = t & 63, w = t >> 6, m = lane & 15, q = lane >> 4;
  const int tile0 = blockIdx.x * EAW_TPB;
  const int ntile = (15625 - tile0 < EAW_TPB) ? (15625 - tile0) : EAW_TPB;
  short8 bfrag[5];
  float bv[5];
#pragma unroll
  for (int ct = 0; ct < 5; ct++) {
    bfrag[ct] = *(const short8*)(Bt + (ct * 16 + m) * 104 + q * 8);
    int c = ct * 16 + m;
    bv[ct] = (c < 66) ? bias[c] : 0.0f;
  }
#pragma unroll
  for (int tl = 0; tl < EAW_TPB; tl++) {
    if (tl < ntile) {
      const int e0 = (tile0 + tl) * 64;
      int p = permS[e0 + w * 16 + m];
      const float* src = eattr + (size_t)p * 32 + q * 8;
      float4 f0 = *(const float4*)src;
      float4 f1 = *(const float4*)(src + 4);
      short8 a;
      a[0] = (short)f2b(f0.x); a[1] = (short)f2b(f0.y);
      a[2] = (short)f2b(f0.z); a[3] = (short)f2b(f0.w);
      a[4] = (short)f2b(f1.x); a[5] = (short)f2b(f1.y);
      a[6] = (short)f2b(f1.z); a[7] = (short)f2b(f1.w);
      f32x4 zero = {};
      f32x4 acc[5];
#pragma unroll
      for (int ct = 0; ct < 5; ct++)
        acc[ct] = __builtin_amdgcn_mfma_f32_16x16x32_bf16(a, bfrag[ct], zero, 0, 0, 0);
#pragma unroll
      for (int ct = 0; ct < 5; ct++) {
        int c = ct * 16 + m;
        if (c < 72) {
#pragma unroll
          for (int r2 = 0; r2 < 4; r2++) {
            int e = w * 16 + q * 4 + r2;
            unsigned short val = (c < 66) ? f2b(acc[ct][r2] + bv[ct])
                                          : (unsigned short)0;
            eaW[(size_t)(e0 + e) * 72 + c] = val;
          }
        }
      }
    }
  }
}

// ---------------------------------------------------------------------------
// Edge-centric aggregation v5: block = 64 dst-sorted edges. eaW/hB rows are
// padded to 144B (36 u32, 16B-aligned, zero pad) so phase A is 4 threads/edge
// x up-to-3 uint4 loads per stream, ALL issued before use. relu(ea+h) ->
// msgS via float4 ds_writes. Phase B: per-(run,col-pair) float2 sums.
// No LDS atomics anywhere (CAS-loop poison).
// ---------------------------------------------------------------------------
__global__ __launch_bounds__(256) void msg_aggr5(
    const int* __restrict__ rowptr, const int* __restrict__ srcS,
    const int* __restrict__ dstS, const unsigned int* __restrict__ eaW32,
    const unsigned int* __restrict__ hB32, float* __restrict__ aggr)
{
  __shared__ float msgS[64 * 76];
  __shared__ int sidx[64], didx[64];
  __shared__ int runStart[65];
  __shared__ int nrunsS;
  const int t = threadIdx.x;
  const int e0 = blockIdx.x * 64;
  if (t < 64) {
    int sv = srcS[e0 + t];
    int dv = dstS[e0 + t];
    sidx[t] = sv; didx[t] = dv;
    int dprev = __shfl_up(dv, 1);
    bool b = (t == 0) || (dv != dprev);
    unsigned long long mask = __ballot(b);
    int below = __popcll(mask & ((1ull << t) - 1ull));
    if (b) runStart[below] = t;
    if (t == 63) { nrunsS = __popcll(mask); runStart[__popcll(mask)] = 64; }
  }
  __syncthreads();
  // ---- phase A: 64 edges x 36 u32, 4 threads/edge, batched uint4 loads ----
  const int e = t >> 2, q = t & 3;
  const unsigned int* ea = eaW32 + (size_t)(e0 + e) * 36;
  const unsigned int* ph = hB32 + (size_t)sidx[e] * 36;
  uint4 a0 = *(const uint4*)(ea + q * 4);
  uint4 h0 = *(const uint4*)(ph + q * 4);
  uint4 a1 = *(const uint4*)(ea + q * 4 + 16);
  uint4 h1 = *(const uint4*)(ph + q * 4 + 16);
  uint4 a2 = {}, h2 = {};
  if (q == 0) { a2 = *(const uint4*)(ea + 32); h2 = *(const uint4*)(ph + 32); }
  float* mrow = msgS + e * 76;
  relu8s(mrow + q * 8, a0, h0);
  relu8s(mrow + q * 8 + 32, a1, h1);
  if (q == 0) relu8s(mrow + 64, a2, h2);
  __syncthreads();
  // ---- phase B: segmented sums, 33 col-pairs per run ----
  const int nr = nrunsS;
  for (int task = t; task < nr * 33; task += 256) {
    int r = task / 33, pp = task - r * 33;
    int c = pp * 2;
    int s0 = runStart[r], s1 = runStart[r + 1];
    float x0 = 0.f, x1 = 0.f, y0 = 0.f, y1 = 0.f;
    int ee = s0;
    for (; ee + 1 < s1; ee += 2) {
      float2 u = *(const float2*)(msgS + ee * 76 + c);
      float2 v = *(const float2*)(msgS + (ee + 1) * 76 + c);
      x0 += u.x; x1 += u.y; y0 += v.x; y1 += v.y;
    }
    if (ee < s1) {
      float2 u = *(const float2*)(msgS + ee * 76 + c);
      x0 += u.x; x1 += u.y;
    }
    x0 += y0; x1 += y1;
    int n = didx[s0];
    bool partial = false;
    if (r == 0)      partial = (rowptr[n] < e0);
    if (r == nr - 1) partial = partial || (rowptr[n + 1] > e0 + 64);
    if (partial) {
      atomicAdd(&aggr[(size_t)n * 66 + c], x0);
      atomicAdd(&aggr[(size_t)n * 66 + c + 1], x1);
    } else {
      float2 s; s.x = x0; s.y = x1;
      *(float2*)(&aggr[(size_t)n * 66 + c]) = s;
    }
  }
}

// ---------------------------------------------------------------------------
// Fallback (ws too small for eaW): fused MFMA message+aggregate, edge-centric.
// ---------------------------------------------------------------------------
__global__ __launch_bounds__(256) void msg_aggr2(
    const int* __restrict__ rowptr, const int* __restrict__ srcS,
    const int* __restrict__ dstS,
    const float* __restrict__ eattr, const int* __restrict__ permS,
    const unsigned short* __restrict__ Bt, const float* __restrict__ bias,
    const unsigned short* __restrict__ hB, float* __restrict__ aggr)
{
  __shared__ __align__(16) unsigned short As[64 * 40];
  __shared__ __align__(16) unsigned short Bs[80 * 104];
  __shared__ float msgS[64 * 67];
  __shared__ float bs[80];
  __shared__ int sidx[64], didx[64];
  __shared__ int runStart[65];
  __shared__ int nrunsS;
  const int t = threadIdx.x;
  const int e0 = blockIdx.x * 64;
  for (int i = t; i < 1040; i += 256) ((uint4*)Bs)[i] = ((const uint4*)Bt)[i];
  if (t < 80) bs[t] = (t < 66) ? bias[t] : 0.0f;
  if (t < 64) { sidx[t] = srcS[e0 + t]; didx[t] = dstS[e0 + t]; }
  for (int i = t; i < 1024; i += 256) {
    int r = i >> 4, j = i & 15;
    int p = permS[e0 + r];
    float2 f = ((const float2*)(eattr + (size_t)p * 32))[j];
    As[r * 40 + j * 2] = f2b(f.x);
    As[r * 40 + j * 2 + 1] = f2b(f.y);
  }
  __syncthreads();
  if (t < 64) {
    int dv = didx[t];
    int dprev = __shfl_up(dv, 1);
    bool b = (t == 0) || (dv != dprev);
    unsigned long long mask = __ballot(b);
    int idx = __popcll(mask & ((1ull << t) - 1ull));
    if (b) runStart[idx] = t;
    if (t == 63) { nrunsS = __popcll(mask); runStart[__popcll(mask)] = 64; }
  }
  const int lane = t & 63, w = t >> 6, m = lane & 15, q = lane >> 4;
  f32x4 acc[5] = {};
  short8 a = *(const short8*)(As + (w * 16 + m) * 40 + q * 8);
#pragma unroll
  for (int ct = 0; ct < 5; ct++) {
    short8 b = *(const short8*)(Bs + (ct * 16 + m) * 104 + q * 8);
    acc[ct] = __builtin_amdgcn_mfma_f32_16x16x32_bf16(a, b, acc[ct], 0, 0, 0);
  }
#pragma unroll
  for (int ct = 0; ct < 5; ct++) {
    int c = ct * 16 + m;
    if (c < 66) {
      float bv = bs[c];
#pragma unroll
      for (int r2 = 0; r2 < 4; r2++) {
        int e = w * 16 + q * 4 + r2;
        float v = acc[ct][r2] + bv + b2f(hB[(size_t)sidx[e] * 72 + c]);
        msgS[e * 67 + c] = fmaxf(v, 0.f);
      }
    }
  }
  __syncthreads();
  const int nr = nrunsS;
  for (int task = t; task < nr * 66; task += 256) {
    int r = task / 66, c = task - r * 66;
    int s0 = runStart[r], s1 = runStart[r + 1];
    float s = 0.0f;
    for (int e = s0; e < s1; e++) s += msgS[e * 67 + c];
    int n = didx[s0];
    bool partial = false;
    if (r == 0)      partial = (rowptr[n] < e0);
    if (r == nr - 1) partial = partial || (rowptr[n + 1] > e0 + 64);
    if (partial) atomicAdd(&aggr[(size_t)n * 66 + c], s);
    else         aggr[(size_t)n * 66 + c] = s;
  }
}

// ---------------------------------------------------------------------------
// BatchNorm stats + update (fp32); bn_update also refreshes hB mirror.
// ---------------------------------------------------------------------------
__global__ __launch_bounds__(256) void bn_stats(const float* __restrict__ z,
                                                float* __restrict__ stat)
{
  const int t = threadIdx.x;
  if (t >= 198) return;
  const int c = t % 66, rs = t / 66;
  const int r0 = blockIdx.x * 1024;
  float s1 = 0.0f, s2 = 0.0f;
  int rend = r0 + 1024; if (rend > NN) rend = NN;
  for (int r = r0 + rs; r < rend; r += 3) {
    float v = z[(size_t)r * 66 + c];
    s1 += v; s2 += v * v;
  }
  atomicAdd(&stat[c], s1);
  atomicAdd(&stat[66 + c], s2);
}

__global__ __launch_bounds__(256) void bn_update(
    float* __restrict__ h, unsigned short* __restrict__ hB,
    const float* __restrict__ z, const float* __restrict__ stat,
    const float* __restrict__ gamma, const float* __restrict__ beta)
{
  int idx = blockIdx.x * 256 + threadIdx.x;
  if (idx >= NN * 66) return;
  int c = idx % 66;
  int r = idx / 66;
  float mean = stat[c] * (1.0f / NN);
  float var  = stat[66 + c] * (1.0f / NN) - mean * mean;
  float inv  = rsqrtf(var + 1e-5f);
  float zn   = (z[idx] - mean) * inv * gamma[c] + beta[c];
  float v = 0.5f * (h[idx] + fmaxf(zn, 0.0f));
  h[idx] = v;
  hB[(size_t)r * 72 + c] = f2b(v);
}

// ---------------------------------------------------------------------------
// Fused edge update (block = 64 target edges), MFMA chain:
//   mid = relu(tea@W1c + b1 + P12[ts,0:66] + P12[td,66:132]);   (P12 bf16)
//   tea += 0.5*(mid@W2 + b2)
// v2: B1t/B2t fragments read directly from global (L2-hot) per ks step —
// no Bs LDS staging (47 KB -> ~14.5 KB, 3 -> 8 blocks/CU).
// ---------------------------------------------------------------------------
__global__ __launch_bounds__(256) void edge_fused2(
    const unsigned short* __restrict__ P12, const int* __restrict__ eli,
    const unsigned short* __restrict__ B1t, const float* __restrict__ b1,
    const unsigned short* __restrict__ B2t, const float* __restrict__ b2,
    float* __restrict__ tea)
{
  __shared__ __align__(16) unsigned short As[64 * 104];  // tea tile, then mid
  __shared__ int sidx[64], didx[64];
  const int t = threadIdx.x;
  const int e0 = blockIdx.x * 64;
  const int lane = t & 63, w = t >> 6, m = lane & 15, q = lane >> 4;
  if (t < 64) { sidx[t] = eli[e0 + t]; didx[t] = eli[NT + e0 + t]; }
  float b1v[5], b2v[5];
#pragma unroll
  for (int ct = 0; ct < 5; ct++) {
    int c = ct * 16 + m;
    b1v[ct] = (c < 66) ? b1[c] : 0.f;
    b2v[ct] = (c < 66) ? b2[c] : 0.f;
  }
  for (int i = t; i < 64 * 48; i += 256) {
    int r = i / 48, kk = (i - r * 48) * 2;
    unsigned short u0 = 0, u1 = 0;
    if (kk < 66) {
      float2 f = *(const float2*)(tea + (size_t)(e0 + r) * 66 + kk);
      u0 = f2b(f.x); u1 = f2b(f.y);
    }
    As[r * 104 + kk] = u0; As[r * 104 + kk + 1] = u1;
  }
  __syncthreads();
  const unsigned short* Ap = As + (w * 16 + m) * 104 + q * 8;
  const unsigned short* Bp1 = B1t + m * 104 + q * 8;
  f32x4 acc[5] = {};
#pragma unroll
  for (int ks = 0; ks < 3; ks++) {
    short8 a = *(const short8*)(Ap + ks * 32);
#pragma unroll
    for (int ct = 0; ct < 5; ct++) {
      short8 b = *(const short8*)(Bp1 + ct * 16 * 104 + ks * 32);
      acc[ct] = __builtin_amdgcn_mfma_f32_16x16x32_bf16(a, b, acc[ct], 0, 0, 0);
    }
  }
  __syncthreads();  // GEMM1 reads of As done before mid overwrite
#pragma unroll
  for (int ct = 0; ct < 5; ct++) {
    int c = ct * 16 + m;
    if (c < 66) {
      float bv = b1v[ct];
#pragma unroll
      for (int r2 = 0; r2 < 4; r2++) {
        int e = w * 16 + q * 4 + r2;
        float v = acc[ct][r2] + bv + b2f(P12[(size_t)sidx[e] * 132 + c])
                                   + b2f(P12[(size_t)didx[e] * 132 + 66 + c]);
        As[e * 104 + c] = f2b(fmaxf(v, 0.f));
      }
    }
  }
  __syncthreads();
  const unsigned short* Bp2 = B2t + m * 104 + q * 8;
  f32x4 acc2[5] = {};
#pragma unroll
  for (int ks = 0; ks < 3; ks++) {
    short8 a = *(const short8*)(Ap + ks * 32);
#pragma unroll
    for (int ct = 0; ct < 5; ct++) {
      short8 b = *(const short8*)(Bp2 + ct * 16 * 104 + ks * 32);
      acc2[ct] = __builtin_amdgcn_mfma_f32_16x16x32_bf16(a, b, acc2[ct], 0, 0, 0);
    }
  }
#pragma unroll
  for (int ct = 0; ct < 5; ct++) {
    int c = ct * 16 + m;
    if (c < 66) {
      float bv = b2v[ct];
#pragma unroll
      for (int r2 = 0; r2 < 4; r2++) {
        int e = w * 16 + q * 4 + r2;
        size_t idx = (size_t)(e0 + e) * 66 + c;
        tea[idx] += 0.5f * (acc2[ct][r2] + bv);
      }
    }
  }
}

// ---------------------------------------------------------------------------
// Fused final classifier (block = 64 target edges):
//   o1 = relu(tea@mw1c + b1 + P12f[ts,0:50] + P12f[td,50:100]);  (P12f bf16)
//   o2 = relu(o1@w2+b2); out = o2@w3+b3
// v2: B1t fragments direct from global; bias in registers.
// ---------------------------------------------------------------------------
__global__ __launch_bounds__(256) void final_fused2(
    const float* __restrict__ tea, const unsigned short* __restrict__ P12f,
    const int* __restrict__ eli, const unsigned short* __restrict__ B1t,
    const float* __restrict__ b1, const float* __restrict__ w2,
    const float* __restrict__ b2, const float* __restrict__ w3,
    const float* __restrict__ b3, float* __restrict__ out)
{
  __shared__ __align__(16) unsigned short As[64 * 104];
  __shared__ float o1s[64 * 51];
  __shared__ float o2s[64 * 25];
  __shared__ float w2s[50 * 25], w3s[50];
  __shared__ float b2s[25], b3s[2];
  __shared__ int sidx[64], didx[64];
  const int t = threadIdx.x;
  const int e0 = blockIdx.x * 64;
  const int lane = t & 63, w = t >> 6, m = lane & 15, q = lane >> 4;
  for (int i = t; i < 50 * 25; i += 256) w2s[i] = w2[i];
  if (t < 50) w3s[t] = w3[t];
  if (t < 64) { sidx[t] = eli[e0 + t]; didx[t] = eli[NT + e0 + t]; }
  if (t < 25) b2s[t] = b2[t];
  if (t < 2)  b3s[t] = b3[t];
  float b1v[4];
#pragma unroll
  for (int ct = 0; ct < 4; ct++) {
    int c = ct * 16 + m;
    b1v[ct] = (c < 50) ? b1[c] : 0.f;
  }
  for (int i = t; i < 64 * 48; i += 256) {
    int r = i / 48, kk = (i - r * 48) * 2;
    unsigned short u0 = 0, u1 = 0;
    if (kk < 66) {
      float2 f = *(const float2*)(tea + (size_t)(e0 + r) * 66 + kk);
      u0 = f2b(f.x); u1 = f2b(f.y);
    }
    As[r * 104 + kk] = u0; As[r * 104 + kk + 1] = u1;
  }
  __syncthreads();
  const unsigned short* Ap = As + (w * 16 + m) * 104 + q * 8;
  const unsigned short* Bp = B1t + m * 104 + q * 8;
  f32x4 acc[4] = {};
#pragma unroll
  for (int ks = 0; ks < 3; ks++) {
    short8 a = *(const short8*)(Ap + ks * 32);
#pragma unroll
    for (int ct = 0; ct < 4; ct++) {
      short8 b = *(const short8*)(Bp + ct * 16 * 104 + ks * 32);
      acc[ct] = __builtin_amdgcn_mfma_f32_16x16x32_bf16(a, b, acc[ct], 0, 0, 0);
    }
  }
#pragma unroll
  for (int ct = 0; ct < 4; ct++) {
    int c = ct * 16 + m;
    if (c < 50) {
      float bv = b1v[ct];
#pragma unroll
      for (int r2 = 0; r2 < 4; r2++) {
        int e = w * 16 + q * 4 + r2;
        float v = acc[ct][r2] + bv + b2f(P12f[(size_t)sidx[e] * 100 + c])
                                   + b2f(P12f[(size_t)didx[e] * 100 + 50 + c]);
        o1s[e * 51 + c] = fmaxf(v, 0.f);
      }
    }
  }
  __syncthreads();
  for (int it = t; it < 64 * 25; it += 256) {
    int e = it / 25, c = it - e * 25;
    float s = b2s[c];
    for (int k = 0; k < 50; k++) s = fmaf(o1s[e * 51 + k], w2s[k * 25 + c], s);
    o2s[e * 25 + c] = fmaxf(s, 0.f);
  }
  __syncthreads();
  if (t < 128) {
    int e = t >> 1, c = t & 1;
    float s = b3s[c];
    for (int k = 0; k < 25; k++) s = fmaf(o2s[e * 25 + k], w3s[k * 2 + c], s);
    out[(size_t)(e0 + e) * 2 + c] = s;
  }
}

// ---------------------------------------------------------------------------
extern "C" void kernel_launch(void* const* d_in, const int* in_sizes, int n_in,
                              void* d_out, int out_size, void* d_ws, size_t ws_size,
                              hipStream_t stream) {
  const float* x      = (const float*)d_in[0];
  const int*   ei     = (const int*)  d_in[1];
  const float* eattr  = (const float*)d_in[2];
  const int*   eli    = (const int*)  d_in[3];
  const float* tattr  = (const float*)d_in[4];
  const float* node_w = (const float*)d_in[5];
  const float* node_b = (const float*)d_in[6];
  const float* edge_w = (const float*)d_in[7];
  const float* edge_b = (const float*)d_in[8];
  const float* cw1    = (const float*)d_in[9];
  const float* cb1    = (const float*)d_in[10];
  const float* cw2    = (const float*)d_in[11];
  const float* cb2    = (const float*)d_in[12];
  const float* bng    = (const float*)d_in[13];
  const float* bnb    = (const float*)d_in[14];
  const float* ew1    = (const float*)d_in[15];
  const float* eb1    = (const float*)d_in[16];
  const float* ew2    = (const float*)d_in[17];
  const float* eb2    = (const float*)d_in[18];
  const float* mw1    = (const float*)d_in[19];
  const float* mb1    = (const float*)d_in[20];
  const float* mw2    = (const float*)d_in[21];
  const float* mb2    = (const float*)d_in[22];
  const float* mw3    = (const float*)d_in[23];
  const float* mb3    = (const float*)d_in[24];
  float* out = (float*)d_out;

  // ---- workspace layout (optional eaW last) ----
  char* p = (char*)d_ws;
  auto alloc = [&](size_t bytes) { void* r = p; p += (bytes + 255) & ~(size_t)255; return r; };
  float* h      = (float*)alloc((size_t)NN * 66 * 4);
  unsigned short* hB = (unsigned short*)alloc((size_t)NN * 72 * 2);  // padded 144B rows
  float* big    = (float*)alloc((size_t)NN * 132 * 4);  // P12(bf16) / midb
  float* zbuf   = (float*)alloc((size_t)NN * 66 * 4);   // aggr / z
  float* tea    = (float*)alloc((size_t)NT * 66 * 4);
  float* stat   = (float*)alloc(1024);
  int*   rowptr = (int*)alloc((NN + 1) * 4);
  int*   cur    = (int*)alloc((size_t)NN * 4);
  int*   bsum   = (int*)alloc((SCB + 1) * 4);
  int*   srcS   = (int*)alloc((size_t)NE * 4);
  int*   dstS   = (int*)alloc((size_t)NE * 4);
  int*   permS  = (int*)alloc((size_t)NE * 4);
  unsigned short* wT = (unsigned short*)alloc((size_t)140000 * 2);
  size_t used = (size_t)(p - (char*)d_ws);
  unsigned short* eaW = nullptr;
  if (ws_size >= used + (size_t)NE * 72 * 2 + 256)
    eaW = (unsigned short*)alloc((size_t)NE * 72 * 2);  // padded 144B rows

  const int gN = (NN + 63) / 64;  // 1563
  const int gT = NT / 64;         // 3125
  const int gE = NE / 64;         // 15625
  const int gEB = (gE + EAW_TPB - 1) / EAW_TPB;  // 1954

  // ---- CSR build ----
  hipMemsetAsync(cur, 0, (size_t)NN * sizeof(int), stream);
  hist_kernel<<<(NE + 255) / 256, 256, 0, stream>>>(ei, cur);
  blocksum_k<<<SCB, 256, 0, stream>>>(cur, bsum);
  scansums_k<<<1, 512, 0, stream>>>(bsum, rowptr);
  scatter_scan_k<<<SCB, 256, 0, stream>>>(cur, bsum, rowptr);
  hipMemsetAsync(cur, 0, (size_t)NN * sizeof(int), stream);
  fill_kernel<<<(NE + 255) / 256, 256, 0, stream>>>(ei, rowptr, cur, srcS, dstS, permS);

  // ---- weight prep ----
  PrepTab tb;
  int offs[14];
  int off = 0;
  auto set = [&](int s, const float* A, const float* B, int K, int C, int rows) {
    tb.a[s] = A; tb.b[s] = B; tb.K[s] = K; tb.C[s] = C; tb.rows[s] = rows;
    tb.off[s] = off; offs[s] = off; off += rows * 104;
  };
  set(0, node_w, nullptr, 64, 66, 80);
  set(1, edge_w, nullptr, 32, 66, 80);
  for (int l = 0; l < 2; l++) {
    set(2 + l, cw1 + (size_t)l * 4356, nullptr, 66, 66, 80);
    set(4 + l, cw2 + (size_t)l * 4356, nullptr, 66, 66, 80);
    set(6 + l, ew1 + (size_t)l * 13068 + 8712, nullptr, 66, 66, 80);       // W1c
    set(8 + l, ew2 + (size_t)l * 4356, nullptr, 66, 66, 80);
    set(10 + l, ew1 + (size_t)l * 13068, ew1 + (size_t)l * 13068 + 4356,   // W1a||W1b
        66, 66, 144);
  }
  set(12, mw1, mw1 + 3300, 66, 50, 112);   // A||B
  set(13, mw1 + 6600, nullptr, 66, 50, 80);  // C
  prep_w<<<14, 256, 0, stream>>>(tb, wT);

  // ---- one-time, layer-invariant ea projection (direct permS gather) ----
  if (eaW)
    eaw_kernel<<<gEB, 256, 0, stream>>>(eattr, permS, wT + offs[1], edge_b, eaW);

  // ---- embeds ----
  mfma_gemm<64, 2, 5, 66, 0, 4><<<gN, 256, 0, stream>>>(
      x, nullptr, wT + offs[0], node_b, h, hB, NN);
  mfma_gemm<32, 1, 5, 66, 0, 0><<<gT, 256, 0, stream>>>(
      tattr, nullptr, wT + offs[1], edge_b, tea, nullptr, NT);

  for (int l = 0; l < 2; l++) {
    // aggregation
    hipMemsetAsync(zbuf, 0, (size_t)NN * 66 * sizeof(float), stream);
    if (eaW)
      msg_aggr5<<<gE, 256, 0, stream>>>(rowptr, srcS, dstS,
                                        (const unsigned int*)eaW,
                                        (const unsigned int*)hB, zbuf);
    else
      msg_aggr2<<<gE, 256, 0, stream>>>(rowptr, srcS, dstS, eattr, permS,
                                        wT + offs[1], edge_b, hB, zbuf);
    // node MLP: midb = bf16(relu((h+aggr)@cw1+b1)); z = midb@cw2+b2
    mfma_gemm<66, 3, 5, 66, 1, 3><<<gN, 256, 0, stream>>>(
        h, zbuf, wT + offs[2 + l], cb1 + l * 66, (unsigned short*)big, nullptr, NN);
    mfma_gemm<66, 3, 5, 66, 3, 0><<<gN, 256, 0, stream>>>(
        (unsigned short*)big, nullptr, wT + offs[4 + l], cb2 + l * 66, zbuf, nullptr, NN);
    // batchnorm + h update (refreshes hB mirror)
    hipMemsetAsync(stat, 0, 132 * sizeof(float), stream);
    bn_stats<<<(NN + 1023) / 1024, 256, 0, stream>>>(zbuf, stat);
    bn_update<<<(NN * 66 + 255) / 256, 256, 0, stream>>>(h, hB, zbuf, stat,
                                                         bng + l * 66, bnb + l * 66);
    // edge update: P12 = bf16(h @ [W1a||W1b]), then fused tile kernel
    mfma_gemm<66, 3, 9, 132, 0, 2><<<gN, 256, 0, stream>>>(
        h, nullptr, wT + offs[10 + l], nullptr, big, nullptr, NN);
    edge_fused2<<<gT, 256, 0, stream>>>((const unsigned short*)big, eli,
                                        wT + offs[6 + l], eb1 + l * 66,
                                        wT + offs[8 + l], eb2 + l * 66, tea);
  }

  // ---- final classifier ----
  mfma_gemm<66, 3, 7, 100, 2, 2><<<gN, 256, 0, stream>>>(
      h, nullptr, wT + offs[12], nullptr, big, nullptr, NN);
  final_fused2<<<gT, 256, 0, stream>>>(tea, (const unsigned short*)big, eli,
                                       wT + offs[13], mb1,
                                       mw2, mb2, mw3, mb3, out);
}

// Round 6
// 1270.423 us; speedup vs baseline: 1.4820x; 1.0075x over previous
//
#include <hip/hip_runtime.h>

#define NN 100000   // nodes
#define NE 1000000  // edges (divisible by 64)
#define NT 200000   // target edges (divisible by 64)
#define SCB 391     // ceil(NN/256) scan blocks
#define EAW_TPB 8   // edge tiles per block in eaw_kernel

typedef __attribute__((ext_vector_type(8))) short short8;
typedef __attribute__((ext_vector_type(4))) float f32x4;

__device__ __forceinline__ unsigned short f2b(float x) {  // fp32 -> bf16 RNE
  union { float f; unsigned int u; } v; v.f = x;
  unsigned int r = v.u + 0x7fffu + ((v.u >> 16) & 1u);
  return (unsigned short)(r >> 16);
}
__device__ __forceinline__ float b2f(unsigned short x) {
  union { unsigned int u; float f; } v; v.u = ((unsigned int)x) << 16;
  return v.f;
}
__device__ __forceinline__ float uif(unsigned int u) {
  union { unsigned int u; float f; } v; v.u = u; return v.f;
}

// unpack 4 u32 (8 bf16) pairs, relu(a+h), store 8 f32 to LDS (two float4s)
__device__ __forceinline__ void relu8s(float* dst, uint4 a, uint4 h) {
  float4 lo, hi;
  lo.x = fmaxf(uif(a.x << 16) + uif(h.x << 16), 0.f);
  lo.y = fmaxf(uif(a.x & 0xffff0000u) + uif(h.x & 0xffff0000u), 0.f);
  lo.z = fmaxf(uif(a.y << 16) + uif(h.y << 16), 0.f);
  lo.w = fmaxf(uif(a.y & 0xffff0000u) + uif(h.y & 0xffff0000u), 0.f);
  hi.x = fmaxf(uif(a.z << 16) + uif(h.z << 16), 0.f);
  hi.y = fmaxf(uif(a.z & 0xffff0000u) + uif(h.z & 0xffff0000u), 0.f);
  hi.z = fmaxf(uif(a.w << 16) + uif(h.w << 16), 0.f);
  hi.w = fmaxf(uif(a.w & 0xffff0000u) + uif(h.w & 0xffff0000u), 0.f);
  *(float4*)dst = lo;
  *(float4*)(dst + 4) = hi;
}

// ---------------------------------------------------------------------------
// Weight prep: up to two fp32 sources [K][C] -> bf16 transposed tile
// [rows][104]; row c<C from A col c, C<=c<2C from B col c-C, rest zero.
// ---------------------------------------------------------------------------
struct PrepTab {
  const float* a[14]; const float* b[14];
  int K[14], C[14], rows[14], off[14];
};

__global__ __launch_bounds__(256) void prep_w(PrepTab tab, unsigned short* wT) {
  int s = blockIdx.x;
  const float* A = tab.a[s];
  const float* B = tab.b[s];
  int K = tab.K[s], C = tab.C[s], rows = tab.rows[s];
  unsigned short* dst = wT + tab.off[s];
  int n = rows * 104;
  for (int i = threadIdx.x; i < n; i += 256) {
    int c = i / 104, k = i - c * 104;
    float v = 0.0f;
    if (k < K) {
      if (c < C) v = A[k * C + c];
      else if (B && c < 2 * C) v = B[k * C + (c - C)];
    }
    dst[i] = f2b(v);
  }
}

// ---------------------------------------------------------------------------
// Generic MFMA row-GEMM: out[R,C] = act(in (+add)) @ W + bias
// AIN: 0=f32, 1=f32+add, 2=relu(f32), 3=bf16 input.
// ROUT bit0=relu, bit1=bf16 out, bit2=also write bf16 mirror to out2
// (mirror stride 72, zero-padded cols 66..71 for the padded hB layout).
// ---------------------------------------------------------------------------
template<int K, int KSTEPS, int CT, int C, int AIN, int ROUT>
__global__ __launch_bounds__(256) void mfma_gemm(
    const void* __restrict__ in, const float* __restrict__ add,
    const unsigned short* __restrict__ Bt, const float* __restrict__ bias,
    void* __restrict__ outp, void* __restrict__ out2, int R)
{
  constexpr int CR = CT * 16;
  __shared__ __align__(16) unsigned short As[64 * 104];
  __shared__ __align__(16) unsigned short Bs[CR * 104];
  __shared__ float bs[CR];
  const int t = threadIdx.x;
  const int r0 = blockIdx.x * 64;
  for (int i = t; i < CT * 208; i += 256) ((uint4*)Bs)[i] = ((const uint4*)Bt)[i];
  if (t < CR) bs[t] = (bias && t < C) ? bias[t] : 0.0f;
  constexpr int KH = KSTEPS * 16;  // float2 slots per row
  for (int i = t; i < 64 * KH; i += 256) {
    int r = i / KH, kk = (i - r * KH) * 2;
    int rg = r0 + r;
    unsigned short u0 = 0, u1 = 0;
    if (rg < R && kk < K) {
      if constexpr (AIN == 3) {
        unsigned int u = ((const unsigned int*)in)[((size_t)rg * K + kk) >> 1];
        u0 = u & 0xffffu; u1 = u >> 16;
      } else {
        float2 f = *(const float2*)((const float*)in + (size_t)rg * K + kk);
        float v0 = f.x, v1 = f.y;
        if constexpr (AIN == 1) {
          float2 g = *(const float2*)(add + (size_t)rg * K + kk);
          v0 += g.x; v1 += g.y;
        }
        if constexpr (AIN == 2) { v0 = fmaxf(v0, 0.f); v1 = fmaxf(v1, 0.f); }
        u0 = f2b(v0); u1 = f2b(v1);
      }
    }
    As[r * 104 + kk] = u0; As[r * 104 + kk + 1] = u1;
  }
  __syncthreads();
  const int lane = t & 63, w = t >> 6, m = lane & 15, q = lane >> 4;
  f32x4 acc[CT] = {};
  const unsigned short* Ap = As + (w * 16 + m) * 104 + q * 8;
  const unsigned short* Bp = Bs + m * 104 + q * 8;
#pragma unroll
  for (int ks = 0; ks < KSTEPS; ks++) {
    short8 a = *(const short8*)(Ap + ks * 32);
#pragma unroll
    for (int ct = 0; ct < CT; ct++) {
      short8 b = *(const short8*)(Bp + ct * 16 * 104 + ks * 32);
      acc[ct] = __builtin_amdgcn_mfma_f32_16x16x32_bf16(a, b, acc[ct], 0, 0, 0);
    }
  }
#pragma unroll
  for (int ct = 0; ct < CT; ct++) {
    int c = ct * 16 + m;
    float bv = bs[c];
#pragma unroll
    for (int r2 = 0; r2 < 4; r2++) {
      int row = r0 + w * 16 + q * 4 + r2;
      if (row < R) {
        if (c < C) {
          float v = acc[ct][r2] + bv;
          if constexpr ((ROUT & 1) != 0) v = fmaxf(v, 0.f);
          if constexpr ((ROUT & 2) != 0)
            ((unsigned short*)outp)[(size_t)row * C + c] = f2b(v);
          else
            ((float*)outp)[(size_t)row * C + c] = v;
          if constexpr ((ROUT & 4) != 0)
            ((unsigned short*)out2)[(size_t)row * 72 + c] = f2b(v);
        } else if constexpr ((ROUT & 4) != 0) {
          if (c < 72) ((unsigned short*)out2)[(size_t)row * 72 + c] = 0;
        }
      }
    }
  }
}

// ---------------------------------------------------------------------------
// CSR build: histogram + 3-pass coalesced scan + fill
// ---------------------------------------------------------------------------
__global__ __launch_bounds__(256) void hist_kernel(const int* __restrict__ ei,
                                                   int* __restrict__ deg)
{
  int e = blockIdx.x * 256 + threadIdx.x;
  if (e < NE) atomicAdd(&deg[ei[NE + e]], 1);
}

__global__ __launch_bounds__(256) void blocksum_k(const int* __restrict__ deg,
                                                  int* __restrict__ bsum)
{
  __shared__ int red[256];
  const int t = threadIdx.x;
  int i = blockIdx.x * 256 + t;
  red[t] = (i < NN) ? deg[i] : 0;
  __syncthreads();
  for (int s = 128; s > 0; s >>= 1) {
    if (t < s) red[t] += red[t + s];
    __syncthreads();
  }
  if (t == 0) bsum[blockIdx.x] = red[0];
}

__global__ __launch_bounds__(512) void scansums_k(int* __restrict__ bsum,
                                                  int* __restrict__ rowptr)
{
  __shared__ int s[512];
  const int t = threadIdx.x;
  s[t] = (t < SCB) ? bsum[t] : 0;
  __syncthreads();
  for (int off = 1; off < 512; off <<= 1) {
    int v = (t >= off) ? s[t - off] : 0;
    __syncthreads();
    s[t] += v;
    __syncthreads();
  }
  if (t < SCB) bsum[t] = (t == 0) ? 0 : s[t - 1];  // exclusive
  if (t == 0) rowptr[NN] = NE;
}

__global__ __launch_bounds__(256) void scatter_scan_k(
    const int* __restrict__ deg, const int* __restrict__ bsum,
    int* __restrict__ rowptr)
{
  __shared__ int s[256];
  const int t = threadIdx.x;
  int i = blockIdx.x * 256 + t;
  int v = (i < NN) ? deg[i] : 0;
  s[t] = v;
  __syncthreads();
  for (int off = 1; off < 256; off <<= 1) {
    int x = (t >= off) ? s[t - off] : 0;
    __syncthreads();
    s[t] += x;
    __syncthreads();
  }
  if (i < NN) rowptr[i] = bsum[blockIdx.x] + s[t] - v;
}

__global__ __launch_bounds__(256) void fill_kernel(
    const int* __restrict__ ei, const int* __restrict__ rowptr,
    int* __restrict__ cur, int* __restrict__ srcS, int* __restrict__ dstS,
    int* __restrict__ permS)
{
  int e = blockIdx.x * 256 + threadIdx.x;
  if (e >= NE) return;
  int d = ei[NE + e];
  int pos = atomicAdd(&cur[d], 1);
  int w = rowptr[d] + pos;
  srcS[w] = ei[e];
  dstS[w] = d;
  permS[w] = e;
}

// ---------------------------------------------------------------------------
// One-time, layer-invariant: eaW[w] = edge_attr[perm[w]] @ edge_w + edge_b
// (dst-sorted, bf16, stride 72 with zero pad). v3: no LDS, no syncs, and
// FULLY BATCHED latency: all 8 permS indices loaded first, then all 16
// gather float4s issued back-to-back into registers (statically indexed),
// then compute/store tiles in order. Counted vmcnt waits drain the queue
// progressively, so tile 0's MFMA+stores overlap tiles 1-7's gathers.
// ---------------------------------------------------------------------------
__global__ __launch_bounds__(256) void eaw_kernel(
    const float* __restrict__ eattr, const int* __restrict__ permS,
    const unsigned short* __restrict__ Bt, const float* __restrict__ bias,
    unsigned short* __restrict__ eaW)
{
  const int t = threadIdx.x;
  const int lane = t & 63, w = t >> 6, m = lane & 15, q = lane >> 4;
  const int tile0 = blockIdx.x * EAW_TPB;
  short8 bfrag[5];
  float bv[5];
#pragma unroll
  for (int ct = 0; ct < 5; ct++) {
    bfrag[ct] = *(const short8*)(Bt + (ct * 16 + m) * 104 + q * 8);
    int c = ct * 16 + m;
    bv[ct] = (c < 66) ? bias[c] : 0.0f;
  }
  // phase 1: all permS indices (independent loads; OOB-clamped for tail)
  int pidx[EAW_TPB];
#pragma unroll
  for (int tl = 0; tl < EAW_TPB; tl++) {
    int eidx = (tile0 + tl) * 64 + w * 16 + m;
    pidx[tl] = permS[eidx < NE ? eidx : 0];
  }
  // phase 2: all gathers issued before any use
  float4 f0[EAW_TPB], f1[EAW_TPB];
#pragma unroll
  for (int tl = 0; tl < EAW_TPB; tl++) {
    const float* src = eattr + (size_t)pidx[tl] * 32 + q * 8;
    f0[tl] = *(const float4*)src;
    f1[tl] = *(const float4*)(src + 4);
  }
  // phase 3: compute + store per tile
#pragma unroll
  for (int tl = 0; tl < EAW_TPB; tl++) {
    const int e0 = (tile0 + tl) * 64;
    if (e0 < NE) {
      short8 a;
      a[0] = (short)f2b(f0[tl].x); a[1] = (short)f2b(f0[tl].y);
      a[2] = (short)f2b(f0[tl].z); a[3] = (short)f2b(f0[tl].w);
      a[4] = (short)f2b(f1[tl].x); a[5] = (short)f2b(f1[tl].y);
      a[6] = (short)f2b(f1[tl].z); a[7] = (short)f2b(f1[tl].w);
      f32x4 zero = {};
      f32x4 acc[5];
#pragma unroll
      for (int ct = 0; ct < 5; ct++)
        acc[ct] = __builtin_amdgcn_mfma_f32_16x16x32_bf16(a, bfrag[ct], zero, 0, 0, 0);
#pragma unroll
      for (int ct = 0; ct < 5; ct++) {
        int c = ct * 16 + m;
        if (c < 72) {
#pragma unroll
          for (int r2 = 0; r2 < 4; r2++) {
            int e = w * 16 + q * 4 + r2;
            unsigned short val = (c < 66) ? f2b(acc[ct][r2] + bv[ct])
                                          : (unsigned short)0;
            eaW[(size_t)(e0 + e) * 72 + c] = val;
          }
        }
      }
    }
  }
}

// ---------------------------------------------------------------------------
// Edge-centric aggregation v5: block = 64 dst-sorted edges. eaW/hB rows are
// padded to 144B (36 u32, 16B-aligned, zero pad) so phase A is 4 threads/edge
// x up-to-3 uint4 loads per stream, ALL issued before use. relu(ea+h) ->
// msgS via float4 ds_writes. Phase B: per-(run,col-pair) float2 sums.
// No LDS atomics anywhere (CAS-loop poison).
// ---------------------------------------------------------------------------
__global__ __launch_bounds__(256) void msg_aggr5(
    const int* __restrict__ rowptr, const int* __restrict__ srcS,
    const int* __restrict__ dstS, const unsigned int* __restrict__ eaW32,
    const unsigned int* __restrict__ hB32, float* __restrict__ aggr)
{
  __shared__ float msgS[64 * 76];
  __shared__ int sidx[64], didx[64];
  __shared__ int runStart[65];
  __shared__ int nrunsS;
  const int t = threadIdx.x;
  const int e0 = blockIdx.x * 64;
  if (t < 64) {
    int sv = srcS[e0 + t];
    int dv = dstS[e0 + t];
    sidx[t] = sv; didx[t] = dv;
    int dprev = __shfl_up(dv, 1);
    bool b = (t == 0) || (dv != dprev);
    unsigned long long mask = __ballot(b);
    int below = __popcll(mask & ((1ull << t) - 1ull));
    if (b) runStart[below] = t;
    if (t == 63) { nrunsS = __popcll(mask); runStart[__popcll(mask)] = 64; }
  }
  __syncthreads();
  // ---- phase A: 64 edges x 36 u32, 4 threads/edge, batched uint4 loads ----
  const int e = t >> 2, q = t & 3;
  const unsigned int* ea = eaW32 + (size_t)(e0 + e) * 36;
  const unsigned int* ph = hB32 + (size_t)sidx[e] * 36;
  uint4 a0 = *(const uint4*)(ea + q * 4);
  uint4 h0 = *(const uint4*)(ph + q * 4);
  uint4 a1 = *(const uint4*)(ea + q * 4 + 16);
  uint4 h1 = *(const uint4*)(ph + q * 4 + 16);
  uint4 a2 = {}, h2 = {};
  if (q == 0) { a2 = *(const uint4*)(ea + 32); h2 = *(const uint4*)(ph + 32); }
  float* mrow = msgS + e * 76;
  relu8s(mrow + q * 8, a0, h0);
  relu8s(mrow + q * 8 + 32, a1, h1);
  if (q == 0) relu8s(mrow + 64, a2, h2);
  __syncthreads();
  // ---- phase B: segmented sums, 33 col-pairs per run ----
  const int nr = nrunsS;
  for (int task = t; task < nr * 33; task += 256) {
    int r = task / 33, pp = task - r * 33;
    int c = pp * 2;
    int s0 = runStart[r], s1 = runStart[r + 1];
    float x0 = 0.f, x1 = 0.f, y0 = 0.f, y1 = 0.f;
    int ee = s0;
    for (; ee + 1 < s1; ee += 2) {
      float2 u = *(const float2*)(msgS + ee * 76 + c);
      float2 v = *(const float2*)(msgS + (ee + 1) * 76 + c);
      x0 += u.x; x1 += u.y; y0 += v.x; y1 += v.y;
    }
    if (ee < s1) {
      float2 u = *(const float2*)(msgS + ee * 76 + c);
      x0 += u.x; x1 += u.y;
    }
    x0 += y0; x1 += y1;
    int n = didx[s0];
    bool partial = false;
    if (r == 0)      partial = (rowptr[n] < e0);
    if (r == nr - 1) partial = partial || (rowptr[n + 1] > e0 + 64);
    if (partial) {
      atomicAdd(&aggr[(size_t)n * 66 + c], x0);
      atomicAdd(&aggr[(size_t)n * 66 + c + 1], x1);
    } else {
      float2 s; s.x = x0; s.y = x1;
      *(float2*)(&aggr[(size_t)n * 66 + c]) = s;
    }
  }
}

// ---------------------------------------------------------------------------
// Fallback (ws too small for eaW): fused MFMA message+aggregate, edge-centric.
// ---------------------------------------------------------------------------
__global__ __launch_bounds__(256) void msg_aggr2(
    const int* __restrict__ rowptr, const int* __restrict__ srcS,
    const int* __restrict__ dstS,
    const float* __restrict__ eattr, const int* __restrict__ permS,
    const unsigned short* __restrict__ Bt, const float* __restrict__ bias,
    const unsigned short* __restrict__ hB, float* __restrict__ aggr)
{
  __shared__ __align__(16) unsigned short As[64 * 40];
  __shared__ __align__(16) unsigned short Bs[80 * 104];
  __shared__ float msgS[64 * 67];
  __shared__ float bs[80];
  __shared__ int sidx[64], didx[64];
  __shared__ int runStart[65];
  __shared__ int nrunsS;
  const int t = threadIdx.x;
  const int e0 = blockIdx.x * 64;
  for (int i = t; i < 1040; i += 256) ((uint4*)Bs)[i] = ((const uint4*)Bt)[i];
  if (t < 80) bs[t] = (t < 66) ? bias[t] : 0.0f;
  if (t < 64) { sidx[t] = srcS[e0 + t]; didx[t] = dstS[e0 + t]; }
  for (int i = t; i < 1024; i += 256) {
    int r = i >> 4, j = i & 15;
    int p = permS[e0 + r];
    float2 f = ((const float2*)(eattr + (size_t)p * 32))[j];
    As[r * 40 + j * 2] = f2b(f.x);
    As[r * 40 + j * 2 + 1] = f2b(f.y);
  }
  __syncthreads();
  if (t < 64) {
    int dv = didx[t];
    int dprev = __shfl_up(dv, 1);
    bool b = (t == 0) || (dv != dprev);
    unsigned long long mask = __ballot(b);
    int idx = __popcll(mask & ((1ull << t) - 1ull));
    if (b) runStart[idx] = t;
    if (t == 63) { nrunsS = __popcll(mask); runStart[__popcll(mask)] = 64; }
  }
  const int lane = t & 63, w = t >> 6, m = lane & 15, q = lane >> 4;
  f32x4 acc[5] = {};
  short8 a = *(const short8*)(As + (w * 16 + m) * 40 + q * 8);
#pragma unroll
  for (int ct = 0; ct < 5; ct++) {
    short8 b = *(const short8*)(Bs + (ct * 16 + m) * 104 + q * 8);
    acc[ct] = __builtin_amdgcn_mfma_f32_16x16x32_bf16(a, b, acc[ct], 0, 0, 0);
  }
#pragma unroll
  for (int ct = 0; ct < 5; ct++) {
    int c = ct * 16 + m;
    if (c < 66) {
      float bv = bs[c];
#pragma unroll
      for (int r2 = 0; r2 < 4; r2++) {
        int e = w * 16 + q * 4 + r2;
        float v = acc[ct][r2] + bv + b2f(hB[(size_t)sidx[e] * 72 + c]);
        msgS[e * 67 + c] = fmaxf(v, 0.f);
      }
    }
  }
  __syncthreads();
  const int nr = nrunsS;
  for (int task = t; task < nr * 66; task += 256) {
    int r = task / 66, c = task - r * 66;
    int s0 = runStart[r], s1 = runStart[r + 1];
    float s = 0.0f;
    for (int e = s0; e < s1; e++) s += msgS[e * 67 + c];
    int n = didx[s0];
    bool partial = false;
    if (r == 0)      partial = (rowptr[n] < e0);
    if (r == nr - 1) partial = partial || (rowptr[n + 1] > e0 + 64);
    if (partial) atomicAdd(&aggr[(size_t)n * 66 + c], s);
    else         aggr[(size_t)n * 66 + c] = s;
  }
}

// ---------------------------------------------------------------------------
// BatchNorm stats + update (fp32); bn_update also refreshes hB mirror.
// ---------------------------------------------------------------------------
__global__ __launch_bounds__(256) void bn_stats(const float* __restrict__ z,
                                                float* __restrict__ stat)
{
  const int t = threadIdx.x;
  if (t >= 198) return;
  const int c = t % 66, rs = t / 66;
  const int r0 = blockIdx.x * 1024;
  float s1 = 0.0f, s2 = 0.0f;
  int rend = r0 + 1024; if (rend > NN) rend = NN;
  for (int r = r0 + rs; r < rend; r += 3) {
    float v = z[(size_t)r * 66 + c];
    s1 += v; s2 += v * v;
  }
  atomicAdd(&stat[c], s1);
  atomicAdd(&stat[66 + c], s2);
}

__global__ __launch_bounds__(256) void bn_update(
    float* __restrict__ h, unsigned short* __restrict__ hB,
    const float* __restrict__ z, const float* __restrict__ stat,
    const float* __restrict__ gamma, const float* __restrict__ beta)
{
  int idx = blockIdx.x * 256 + threadIdx.x;
  if (idx >= NN * 66) return;
  int c = idx % 66;
  int r = idx / 66;
  float mean = stat[c] * (1.0f / NN);
  float var  = stat[66 + c] * (1.0f / NN) - mean * mean;
  float inv  = rsqrtf(var + 1e-5f);
  float zn   = (z[idx] - mean) * inv * gamma[c] + beta[c];
  float v = 0.5f * (h[idx] + fmaxf(zn, 0.0f));
  h[idx] = v;
  hB[(size_t)r * 72 + c] = f2b(v);
}

// ---------------------------------------------------------------------------
// Fused edge update (block = 64 target edges), MFMA chain:
//   mid = relu(tea@W1c + b1 + P12[ts,0:66] + P12[td,66:132]);   (P12 bf16)
//   tea += 0.5*(mid@W2 + b2)
// v2: B1t/B2t fragments read directly from global (L2-hot) per ks step —
// no Bs LDS staging (47 KB -> ~14.5 KB, 3 -> 8 blocks/CU).
// ---------------------------------------------------------------------------
__global__ __launch_bounds__(256) void edge_fused2(
    const unsigned short* __restrict__ P12, const int* __restrict__ eli,
    const unsigned short* __restrict__ B1t, const float* __restrict__ b1,
    const unsigned short* __restrict__ B2t, const float* __restrict__ b2,
    float* __restrict__ tea)
{
  __shared__ __align__(16) unsigned short As[64 * 104];  // tea tile, then mid
  __shared__ int sidx[64], didx[64];
  const int t = threadIdx.x;
  const int e0 = blockIdx.x * 64;
  const int lane = t & 63, w = t >> 6, m = lane & 15, q = lane >> 4;
  if (t < 64) { sidx[t] = eli[e0 + t]; didx[t] = eli[NT + e0 + t]; }
  float b1v[5], b2v[5];
#pragma unroll
  for (int ct = 0; ct < 5; ct++) {
    int c = ct * 16 + m;
    b1v[ct] = (c < 66) ? b1[c] : 0.f;
    b2v[ct] = (c < 66) ? b2[c] : 0.f;
  }
  for (int i = t; i < 64 * 48; i += 256) {
    int r = i / 48, kk = (i - r * 48) * 2;
    unsigned short u0 = 0, u1 = 0;
    if (kk < 66) {
      float2 f = *(const float2*)(tea + (size_t)(e0 + r) * 66 + kk);
      u0 = f2b(f.x); u1 = f2b(f.y);
    }
    As[r * 104 + kk] = u0; As[r * 104 + kk + 1] = u1;
  }
  __syncthreads();
  const unsigned short* Ap = As + (w * 16 + m) * 104 + q * 8;
  const unsigned short* Bp1 = B1t + m * 104 + q * 8;
  f32x4 acc[5] = {};
#pragma unroll
  for (int ks = 0; ks < 3; ks++) {
    short8 a = *(const short8*)(Ap + ks * 32);
#pragma unroll
    for (int ct = 0; ct < 5; ct++) {
      short8 b = *(const short8*)(Bp1 + ct * 16 * 104 + ks * 32);
      acc[ct] = __builtin_amdgcn_mfma_f32_16x16x32_bf16(a, b, acc[ct], 0, 0, 0);
    }
  }
  __syncthreads();  // GEMM1 reads of As done before mid overwrite
#pragma unroll
  for (int ct = 0; ct < 5; ct++) {
    int c = ct * 16 + m;
    if (c < 66) {
      float bv = b1v[ct];
#pragma unroll
      for (int r2 = 0; r2 < 4; r2++) {
        int e = w * 16 + q * 4 + r2;
        float v = acc[ct][r2] + bv + b2f(P12[(size_t)sidx[e] * 132 + c])
                                   + b2f(P12[(size_t)didx[e] * 132 + 66 + c]);
        As[e * 104 + c] = f2b(fmaxf(v, 0.f));
      }
    }
  }
  __syncthreads();
  const unsigned short* Bp2 = B2t + m * 104 + q * 8;
  f32x4 acc2[5] = {};
#pragma unroll
  for (int ks = 0; ks < 3; ks++) {
    short8 a = *(const short8*)(Ap + ks * 32);
#pragma unroll
    for (int ct = 0; ct < 5; ct++) {
      short8 b = *(const short8*)(Bp2 + ct * 16 * 104 + ks * 32);
      acc2[ct] = __builtin_amdgcn_mfma_f32_16x16x32_bf16(a, b, acc2[ct], 0, 0, 0);
    }
  }
#pragma unroll
  for (int ct = 0; ct < 5; ct++) {
    int c = ct * 16 + m;
    if (c < 66) {
      float bv = b2v[ct];
#pragma unroll
      for (int r2 = 0; r2 < 4; r2++) {
        int e = w * 16 + q * 4 + r2;
        size_t idx = (size_t)(e0 + e) * 66 + c;
        tea[idx] += 0.5f * (acc2[ct][r2] + bv);
      }
    }
  }
}

// ---------------------------------------------------------------------------
// Fused final classifier (block = 64 target edges):
//   o1 = relu(tea@mw1c + b1 + P12f[ts,0:50] + P12f[td,50:100]);  (P12f bf16)
//   o2 = relu(o1@w2+b2); out = o2@w3+b3
// v2: B1t fragments direct from global; bias in registers.
// ---------------------------------------------------------------------------
__global__ __launch_bounds__(256) void final_fused2(
    const float* __restrict__ tea, const unsigned short* __restrict__ P12f,
    const int* __restrict__ eli, const unsigned short* __restrict__ B1t,
    const float* __restrict__ b1, const float* __restrict__ w2,
    const float* __restrict__ b2, const float* __restrict__ w3,
    const float* __restrict__ b3, float* __restrict__ out)
{
  __shared__ __align__(16) unsigned short As[64 * 104];
  __shared__ float o1s[64 * 51];
  __shared__ float o2s[64 * 25];
  __shared__ float w2s[50 * 25], w3s[50];
  __shared__ float b2s[25], b3s[2];
  __shared__ int sidx[64], didx[64];
  const int t = threadIdx.x;
  const int e0 = blockIdx.x * 64;
  const int lane = t & 63, w = t >> 6, m = lane & 15, q = lane >> 4;
  for (int i = t; i < 50 * 25; i += 256) w2s[i] = w2[i];
  if (t < 50) w3s[t] = w3[t];
  if (t < 64) { sidx[t] = eli[e0 + t]; didx[t] = eli[NT + e0 + t]; }
  if (t < 25) b2s[t] = b2[t];
  if (t < 2)  b3s[t] = b3[t];
  float b1v[4];
#pragma unroll
  for (int ct = 0; ct < 4; ct++) {
    int c = ct * 16 + m;
    b1v[ct] = (c < 50) ? b1[c] : 0.f;
  }
  for (int i = t; i < 64 * 48; i += 256) {
    int r = i / 48, kk = (i - r * 48) * 2;
    unsigned short u0 = 0, u1 = 0;
    if (kk < 66) {
      float2 f = *(const float2*)(tea + (size_t)(e0 + r) * 66 + kk);
      u0 = f2b(f.x); u1 = f2b(f.y);
    }
    As[r * 104 + kk] = u0; As[r * 104 + kk + 1] = u1;
  }
  __syncthreads();
  const unsigned short* Ap = As + (w * 16 + m) * 104 + q * 8;
  const unsigned short* Bp = B1t + m * 104 + q * 8;
  f32x4 acc[4] = {};
#pragma unroll
  for (int ks = 0; ks < 3; ks++) {
    short8 a = *(const short8*)(Ap + ks * 32);
#pragma unroll
    for (int ct = 0; ct < 4; ct++) {
      short8 b = *(const short8*)(Bp + ct * 16 * 104 + ks * 32);
      acc[ct] = __builtin_amdgcn_mfma_f32_16x16x32_bf16(a, b, acc[ct], 0, 0, 0);
    }
  }
#pragma unroll
  for (int ct = 0; ct < 4; ct++) {
    int c = ct * 16 + m;
    if (c < 50) {
      float bv = b1v[ct];
#pragma unroll
      for (int r2 = 0; r2 < 4; r2++) {
        int e = w * 16 + q * 4 + r2;
        float v = acc[ct][r2] + bv + b2f(P12f[(size_t)sidx[e] * 100 + c])
                                   + b2f(P12f[(size_t)didx[e] * 100 + 50 + c]);
        o1s[e * 51 + c] = fmaxf(v, 0.f);
      }
    }
  }
  __syncthreads();
  for (int it = t; it < 64 * 25; it += 256) {
    int e = it / 25, c = it - e * 25;
    float s = b2s[c];
    for (int k = 0; k < 50; k++) s = fmaf(o1s[e * 51 + k], w2s[k * 25 + c], s);
    o2s[e * 25 + c] = fmaxf(s, 0.f);
  }
  __syncthreads();
  if (t < 128) {
    int e = t >> 1, c = t & 1;
    float s = b3s[c];
    for (int k = 0; k < 25; k++) s = fmaf(o2s[e * 25 + k], w3s[k * 2 + c], s);
    out[(size_t)(e0 + e) * 2 + c] = s;
  }
}

// ---------------------------------------------------------------------------
extern "C" void kernel_launch(void* const* d_in, const int* in_sizes, int n_in,
                              void* d_out, int out_size, void* d_ws, size_t ws_size,
                              hipStream_t stream) {
  const float* x      = (const float*)d_in[0];
  const int*   ei     = (const int*)  d_in[1];
  const float* eattr  = (const float*)d_in[2];
  const int*   eli    = (const int*)  d_in[3];
  const float* tattr  = (const float*)d_in[4];
  const float* node_w = (const float*)d_in[5];
  const float* node_b = (const float*)d_in[6];
  const float* edge_w = (const float*)d_in[7];
  const float* edge_b = (const float*)d_in[8];
  const float* cw1    = (const float*)d_in[9];
  const float* cb1    = (const float*)d_in[10];
  const float* cw2    = (const float*)d_in[11];
  const float* cb2    = (const float*)d_in[12];
  const float* bng    = (const float*)d_in[13];
  const float* bnb    = (const float*)d_in[14];
  const float* ew1    = (const float*)d_in[15];
  const float* eb1    = (const float*)d_in[16];
  const float* ew2    = (const float*)d_in[17];
  const float* eb2    = (const float*)d_in[18];
  const float* mw1    = (const float*)d_in[19];
  const float* mb1    = (const float*)d_in[20];
  const float* mw2    = (const float*)d_in[21];
  const float* mb2    = (const float*)d_in[22];
  const float* mw3    = (const float*)d_in[23];
  const float* mb3    = (const float*)d_in[24];
  float* out = (float*)d_out;

  // ---- workspace layout (optional eaW last) ----
  char* p = (char*)d_ws;
  auto alloc = [&](size_t bytes) { void* r = p; p += (bytes + 255) & ~(size_t)255; return r; };
  float* h      = (float*)alloc((size_t)NN * 66 * 4);
  unsigned short* hB = (unsigned short*)alloc((size_t)NN * 72 * 2);  // padded 144B rows
  float* big    = (float*)alloc((size_t)NN * 132 * 4);  // P12(bf16) / midb
  float* zbuf   = (float*)alloc((size_t)NN * 66 * 4);   // aggr / z
  float* tea    = (float*)alloc((size_t)NT * 66 * 4);
  float* stat   = (float*)alloc(1024);
  int*   rowptr = (int*)alloc((NN + 1) * 4);
  int*   cur    = (int*)alloc((size_t)NN * 4);
  int*   bsum   = (int*)alloc((SCB + 1) * 4);
  int*   srcS   = (int*)alloc((size_t)NE * 4);
  int*   dstS   = (int*)alloc((size_t)NE * 4);
  int*   permS  = (int*)alloc((size_t)NE * 4);
  unsigned short* wT = (unsigned short*)alloc((size_t)140000 * 2);
  size_t used = (size_t)(p - (char*)d_ws);
  unsigned short* eaW = nullptr;
  if (ws_size >= used + (size_t)NE * 72 * 2 + 256)
    eaW = (unsigned short*)alloc((size_t)NE * 72 * 2);  // padded 144B rows

  const int gN = (NN + 63) / 64;  // 1563
  const int gT = NT / 64;         // 3125
  const int gE = NE / 64;         // 15625
  const int gEB = (gE + EAW_TPB - 1) / EAW_TPB;  // 1954

  // ---- CSR build ----
  hipMemsetAsync(cur, 0, (size_t)NN * sizeof(int), stream);
  hist_kernel<<<(NE + 255) / 256, 256, 0, stream>>>(ei, cur);
  blocksum_k<<<SCB, 256, 0, stream>>>(cur, bsum);
  scansums_k<<<1, 512, 0, stream>>>(bsum, rowptr);
  scatter_scan_k<<<SCB, 256, 0, stream>>>(cur, bsum, rowptr);
  hipMemsetAsync(cur, 0, (size_t)NN * sizeof(int), stream);
  fill_kernel<<<(NE + 255) / 256, 256, 0, stream>>>(ei, rowptr, cur, srcS, dstS, permS);

  // ---- weight prep ----
  PrepTab tb;
  int offs[14];
  int off = 0;
  auto set = [&](int s, const float* A, const float* B, int K, int C, int rows) {
    tb.a[s] = A; tb.b[s] = B; tb.K[s] = K; tb.C[s] = C; tb.rows[s] = rows;
    tb.off[s] = off; offs[s] = off; off += rows * 104;
  };
  set(0, node_w, nullptr, 64, 66, 80);
  set(1, edge_w, nullptr, 32, 66, 80);
  for (int l = 0; l < 2; l++) {
    set(2 + l, cw1 + (size_t)l * 4356, nullptr, 66, 66, 80);
    set(4 + l, cw2 + (size_t)l * 4356, nullptr, 66, 66, 80);
    set(6 + l, ew1 + (size_t)l * 13068 + 8712, nullptr, 66, 66, 80);       // W1c
    set(8 + l, ew2 + (size_t)l * 4356, nullptr, 66, 66, 80);
    set(10 + l, ew1 + (size_t)l * 13068, ew1 + (size_t)l * 13068 + 4356,   // W1a||W1b
        66, 66, 144);
  }
  set(12, mw1, mw1 + 3300, 66, 50, 112);   // A||B
  set(13, mw1 + 6600, nullptr, 66, 50, 80);  // C
  prep_w<<<14, 256, 0, stream>>>(tb, wT);

  // ---- one-time, layer-invariant ea projection (direct permS gather) ----
  if (eaW)
    eaw_kernel<<<gEB, 256, 0, stream>>>(eattr, permS, wT + offs[1], edge_b, eaW);

  // ---- embeds ----
  mfma_gemm<64, 2, 5, 66, 0, 4><<<gN, 256, 0, stream>>>(
      x, nullptr, wT + offs[0], node_b, h, hB, NN);
  mfma_gemm<32, 1, 5, 66, 0, 0><<<gT, 256, 0, stream>>>(
      tattr, nullptr, wT + offs[1], edge_b, tea, nullptr, NT);

  for (int l = 0; l < 2; l++) {
    // aggregation
    hipMemsetAsync(zbuf, 0, (size_t)NN * 66 * sizeof(float), stream);
    if (eaW)
      msg_aggr5<<<gE, 256, 0, stream>>>(rowptr, srcS, dstS,
                                        (const unsigned int*)eaW,
                                        (const unsigned int*)hB, zbuf);
    else
      msg_aggr2<<<gE, 256, 0, stream>>>(rowptr, srcS, dstS, eattr, permS,
                                        wT + offs[1], edge_b, hB, zbuf);
    // node MLP: midb = bf16(relu((h+aggr)@cw1+b1)); z = midb@cw2+b2
    mfma_gemm<66, 3, 5, 66, 1, 3><<<gN, 256, 0, stream>>>(
        h, zbuf, wT + offs[2 + l], cb1 + l * 66, (unsigned short*)big, nullptr, NN);
    mfma_gemm<66, 3, 5, 66, 3, 0><<<gN, 256, 0, stream>>>(
        (unsigned short*)big, nullptr, wT + offs[4 + l], cb2 + l * 66, zbuf, nullptr, NN);
    // batchnorm + h update (refreshes hB mirror)
    hipMemsetAsync(stat, 0, 132 * sizeof(float), stream);
    bn_stats<<<(NN + 1023) / 1024, 256, 0, stream>>>(zbuf, stat);
    bn_update<<<(NN * 66 + 255) / 256, 256, 0, stream>>>(h, hB, zbuf, stat,
                                                         bng + l * 66, bnb + l * 66);
    // edge update: P12 = bf16(h @ [W1a||W1b]), then fused tile kernel
    mfma_gemm<66, 3, 9, 132, 0, 2><<<gN, 256, 0, stream>>>(
        h, nullptr, wT + offs[10 + l], nullptr, big, nullptr, NN);
    edge_fused2<<<gT, 256, 0, stream>>>((const unsigned short*)big, eli,
                                        wT + offs[6 + l], eb1 + l * 66,
                                        wT + offs[8 + l], eb2 + l * 66, tea);
  }

  // ---- final classifier ----
  mfma_gemm<66, 3, 7, 100, 2, 2><<<gN, 256, 0, stream>>>(
      h, nullptr, wT + offs[12], nullptr, big, nullptr, NN);
  final_fused2<<<gT, 256, 0, stream>>>(tea, (const unsigned short*)big, eli,
                                       wT + offs[13], mb1,
                                       mw2, mb2, mw3, mb3, out);
}